// Round 2
// baseline (28431.497 us; speedup 1.0000x reference)
//
#include <hip/hip_runtime.h>
#include <math.h>

#define VOCAB 8000
#define DIM 512
#define NLAYER 8
#define NHEAD 8
#define BATCH 16
#define TMAX 80
#define PROMPT_LEN 64
#define NNEW 16
#define HEADD 64
#define ATT_SCALE 0.125f

#define SRC_PLAIN 0
#define SRC_LN 1
#define SRC_GELU 2

// persistent decode kernel grid (blocks). 128 blocks x 512 thr, ~34KB LDS each:
// <=4 blocks/CU by every resource on 256 CUs -> all blocks co-resident, spin barrier safe.
#define GRIDN 128
// flag stride in u32 units: 128B per flag line to avoid false sharing
#define FLAG_STRIDE 32

__device__ __forceinline__ float gelu_f(float x) {
  return 0.5f * x * (1.0f + tanhf(0.7978845608028654f * (x + 0.044715f * x * x * x)));
}

// ---------------- init ----------------
__global__ void k_init(const int* __restrict__ ids_in, const int* __restrict__ mask_in,
                       int* __restrict__ ids, int* __restrict__ lens, int* __restrict__ fin,
                       float* __restrict__ csum, float* __restrict__ ccnt,
                       unsigned* __restrict__ flags) {
  int tid = threadIdx.x;
  for (int i = tid; i < BATCH * TMAX; i += blockDim.x) ids[i] = ids_in[i];
  // zero all barrier flag lines (graph replays reuse the workspace)
  for (int i = tid; i < GRIDN * FLAG_STRIDE; i += blockDim.x) flags[i] = 0u;
  if (tid < BATCH) {
    int s = 0;
    for (int t = 0; t < TMAX; ++t) s += mask_in[tid * TMAX + t];
    lens[tid] = s;
    fin[tid] = 0;
    csum[tid] = 0.f;
    ccnt[tid] = 0.f;
  }
}

// ---------------- prefill embedding ----------------
__global__ void k_embed_prefill(const int* __restrict__ ids, const float* __restrict__ wte,
                                const float* __restrict__ wpe, float* __restrict__ x) {
  int bt = blockIdx.x;
  int b = bt / PROMPT_LEN, t = bt % PROMPT_LEN;
  int tok = ids[b * TMAX + t];
  for (int d = threadIdx.x; d < DIM; d += blockDim.x)
    x[(size_t)bt * DIM + d] = wte[(size_t)tok * DIM + d] + wpe[(size_t)t * DIM + d];
}

// ---------------- prefill layernorm ----------------
__global__ void k_layernorm(const float* __restrict__ x, const float* __restrict__ w,
                            const float* __restrict__ b, float* __restrict__ out) {
  int row = blockIdx.x;
  int tid = threadIdx.x;
  const float* xr = x + (size_t)row * DIM;
  __shared__ float red[256];
  float v0 = xr[tid], v1 = xr[tid + 256];
  red[tid] = v0 + v1;
  __syncthreads();
  for (int s = 128; s > 0; s >>= 1) {
    if (tid < s) red[tid] += red[tid + s];
    __syncthreads();
  }
  float mean = red[0] * (1.0f / DIM);
  __syncthreads();
  float d0 = v0 - mean, d1 = v1 - mean;
  red[tid] = d0 * d0 + d1 * d1;
  __syncthreads();
  for (int s = 128; s > 0; s >>= 1) {
    if (tid < s) red[tid] += red[tid + s];
    __syncthreads();
  }
  float rstd = 1.0f / sqrtf(red[0] * (1.0f / DIM) + 1e-5f);
  out[(size_t)row * DIM + tid] = d0 * rstd * w[tid] + b[tid];
  out[(size_t)row * DIM + tid + 256] = d1 * rstd * w[tid + 256] + b[tid + 256];
}

// ---------------- prefill tiled GEMM ----------------
// MODE: 1 = gelu(+bias), 2 = +bias +res, 3 = qkv epilogue (+bias, write q + KV caches)
template <int MODE>
__global__ __launch_bounds__(256) void gemm_kernel(const float* __restrict__ A,
                                                   const float* __restrict__ W,
                                                   const float* __restrict__ bias,
                                                   const float* __restrict__ res,
                                                   float* __restrict__ C, int M, int N, int K,
                                                   float* __restrict__ kcT,
                                                   float* __restrict__ vc) {
  const int BM = 64, BN = 64, BK = 16;
  __shared__ float As[BK][BM + 4];
  __shared__ float Ws[BK][BN];
  int tid = threadIdx.x;
  int bm = blockIdx.y * BM, bn = blockIdx.x * BN;
  int tr = tid / 16, tc = tid % 16;
  float acc[4][4];
#pragma unroll
  for (int i = 0; i < 4; i++)
#pragma unroll
    for (int j = 0; j < 4; j++) acc[i][j] = 0.f;

  for (int k0 = 0; k0 < K; k0 += BK) {
    for (int i = tid; i < BM * BK; i += 256) {
      int m = i / BK, kk = i % BK;
      As[kk][m] = A[(size_t)(bm + m) * K + k0 + kk];
    }
    for (int i = tid; i < BK * BN; i += 256) {
      int kk = i / BN, n = i % BN;
      Ws[kk][n] = W[(size_t)(k0 + kk) * N + bn + n];
    }
    __syncthreads();
#pragma unroll
    for (int kk = 0; kk < BK; ++kk) {
      float a[4], w[4];
#pragma unroll
      for (int i = 0; i < 4; i++) a[i] = As[kk][tr * 4 + i];
#pragma unroll
      for (int j = 0; j < 4; j++) w[j] = Ws[kk][tc * 4 + j];
#pragma unroll
      for (int i = 0; i < 4; i++)
#pragma unroll
        for (int j = 0; j < 4; j++) acc[i][j] += a[i] * w[j];
    }
    __syncthreads();
  }
#pragma unroll
  for (int i = 0; i < 4; i++) {
    int m = bm + tr * 4 + i;
#pragma unroll
    for (int j = 0; j < 4; j++) {
      int n = bn + tc * 4 + j;
      float v = acc[i][j] + (bias ? bias[n] : 0.f);
      if (MODE == 1) v = gelu_f(v);
      if (MODE == 2) v += res[(size_t)m * N + n];
      if (MODE == 3) {
        int b = m >> 6, t = m & 63;
        if (n < DIM) {
          C[(size_t)m * N + n] = v;  // q (only q region consumed)
        } else if (n < 2 * DIM) {
          int dd = n - DIM;
          kcT[((size_t)(b * NHEAD + (dd >> 6)) * HEADD + (dd & 63)) * TMAX + t] = v;
        } else {
          int dd = n - 2 * DIM;
          vc[((size_t)(b * NHEAD + (dd >> 6)) * TMAX + t) * HEADD + (dd & 63)] = v;
        }
      } else {
        C[(size_t)m * N + n] = v;
      }
    }
  }
}

// ---------------- prefill attention (K^T cache layout) ----------------
__global__ void k_attn_prefill(const float* __restrict__ qkv, const float* __restrict__ kcT,
                               const float* __restrict__ vc, float* __restrict__ o) {
  int blk = blockIdx.x;
  int q = blk % PROMPT_LEN;
  int bh = blk / PROMPT_LEN;
  int h = bh % NHEAD, b = bh / NHEAD;
  int tid = threadIdx.x;  // 64
  __shared__ float qs[HEADD];
  __shared__ float ps[PROMPT_LEN];
  qs[tid] = qkv[(size_t)(b * PROMPT_LEN + q) * 3 * DIM + h * HEADD + tid];
  __syncthreads();
  const float* kbT = kcT + (size_t)(b * NHEAD + h) * HEADD * TMAX;  // [64][80]
  const float* vb = vc + (size_t)(b * NHEAD + h) * TMAX * HEADD;    // [80][64]
  float s = -1e30f;
  if (tid <= q) {
    float a = 0.f;
    for (int d = 0; d < HEADD; ++d) a += qs[d] * kbT[d * TMAX + tid];
    s = a * ATT_SCALE;
  }
  float mx = s;
  for (int off = 32; off > 0; off >>= 1) mx = fmaxf(mx, __shfl_xor(mx, off));
  float e = (tid <= q) ? expf(s - mx) : 0.f;
  float sum = e;
  for (int off = 32; off > 0; off >>= 1) sum += __shfl_xor(sum, off);
  ps[tid] = e / sum;
  __syncthreads();
  float acc = 0.f;
  for (int t = 0; t <= q; ++t) acc += ps[t] * vb[t * HEADD + tid];
  o[(size_t)(b * PROMPT_LEN + q) * DIM + h * HEADD + tid] = acc;
}

// ================= persistent decode kernel =================

struct SmGemm {
  float sm[DIM * BATCH];  // 8192 floats, max SROWS*BATCH over all stages
  float wsum[8][BATCH];
  float wss[8][BATCH];
  float smean[BATCH], srstd[BATCH];
};
struct SmAttn {
  float qs[8][HEADD];
  float ps[8][TMAX];
};
struct SmUpd {
  float vred[512];
  int ired[512];
  int sh_tok, sh_pos;
};
union SmAll {
  SmGemm g;
  SmAttn a;
  SmUpd u;
};

// All-to-all flag grid barrier. Each block owns one 128B-spaced flag line
// (release store, no RMW contention). Threads 0..GRIDN-1 each poll ONE flag
// (read sharing, no exclusive-ownership ping-pong). Cost ~= one cross-XCD
// visibility round-trip, vs 128 serialized atomic RMWs on a single line.
__device__ __forceinline__ void gsync(unsigned* __restrict__ flags, unsigned gen) {
  __syncthreads();
  if (threadIdx.x == 0)
    __hip_atomic_store(&flags[(unsigned)blockIdx.x * FLAG_STRIDE], gen, __ATOMIC_RELEASE,
                       __HIP_MEMORY_SCOPE_AGENT);
  if (threadIdx.x < GRIDN) {
    while (__hip_atomic_load(&flags[threadIdx.x * FLAG_STRIDE], __ATOMIC_RELAXED,
                             __HIP_MEMORY_SCOPE_AGENT) < gen)
      __builtin_amdgcn_s_sleep(1);
  }
  __threadfence();  // acquire: make remote data visible to this CU
  __syncthreads();
}

// ---------------- decode skinny GEMM stage (device fn; 512 threads) ----------------
// C[16,N] = A^T[16,K] @ W[K,N]. A ([K][16]) is built in LDS from:
//   SRC_PLAIN: src            SRC_LN: ln(src + sum parts) (full-K stage; opt. write xd)
//   SRC_GELU: gelu(sum parts)
// 8 waves = 2 batch-groups x 4 k-chunks. KB = cross-block split-K (partials out,
// bias folded into partial kb==0). LAYOUT: 0 row-major [kb][16][N], 1 transposed [kb][N][16].
template <int KB, int SRC, int P, int LAYOUT, bool BIAS, bool XDW, int N, int K>
__device__ __forceinline__ void skinny_stage(SmGemm& S, int bx, int by,
                                             const float* __restrict__ src,
                                             const float* __restrict__ parts,
                                             const float* __restrict__ lnw,
                                             const float* __restrict__ lnb,
                                             const float* __restrict__ bias,
                                             const float* __restrict__ W, float* __restrict__ out,
                                             float* __restrict__ xdout) {
  constexpr int KRANGE = K / KB;
  constexpr int SROWS = (SRC == SRC_LN) ? K : KRANGE;
  float* sm = S.sm;
  const int tid = threadIdx.x;
  const int base_row = (SRC == SRC_LN) ? 0 : by * KRANGE;

  // ---- stage ----
  {
    const float4* s4 = (const float4*)src;
    float4* d4 = (float4*)sm;
    constexpr int NF4 = SROWS * BATCH / 4;
    for (int i = tid; i < NF4; i += 512) {
      int gi = base_row * (BATCH / 4) + i;
      float4 v;
      if (SRC == SRC_GELU) {
        v = make_float4(0.f, 0.f, 0.f, 0.f);
      } else {
        v = s4[gi];
      }
#pragma unroll
      for (int p = 0; p < P; ++p) {
        const float4* p4 = (const float4*)(parts + (size_t)p * K * BATCH);
        float4 t = p4[gi];
        v.x += t.x;
        v.y += t.y;
        v.z += t.z;
        v.w += t.w;
      }
      if (SRC == SRC_GELU) {
        v.x = gelu_f(v.x);
        v.y = gelu_f(v.y);
        v.z = gelu_f(v.z);
        v.w = gelu_f(v.w);
      }
      if (XDW) {
        if (bx == 0 && by == 0) ((float4*)xdout)[gi] = v;
      }
      d4[i] = v;
    }
  }
  if (SRC == SRC_LN) {
    __syncthreads();
    float s = 0.f, ss = 0.f;
#pragma unroll
    for (int j = 0; j < 16; ++j) {
      float v = sm[tid + 512 * j];
      s += v;
      ss += v * v;
    }
    s += __shfl_xor(s, 16);
    ss += __shfl_xor(ss, 16);
    s += __shfl_xor(s, 32);
    ss += __shfl_xor(ss, 32);
    int lane0 = tid & 63, w0 = tid >> 6;
    if (lane0 < BATCH) {
      S.wsum[w0][lane0] = s;
      S.wss[w0][lane0] = ss;
    }
    __syncthreads();
    if (tid < BATCH) {
      float ts = 0.f, tss = 0.f;
#pragma unroll
      for (int ww = 0; ww < 8; ++ww) {
        ts += S.wsum[ww][tid];
        tss += S.wss[ww][tid];
      }
      float m = ts * (1.0f / K);
      float var = tss * (1.0f / K) - m * m;
      S.smean[tid] = m;
      S.srstd[tid] = 1.0f / sqrtf(var + 1e-5f);
    }
    __syncthreads();
    float mb = S.smean[tid & 15];
    float rb = S.srstd[tid & 15];
#pragma unroll
    for (int j = 0; j < 16; ++j) {
      int idx = tid + 512 * j;
      int k = idx >> 4;
      sm[idx] = (sm[idx] - mb) * rb * lnw[k] + lnb[k];
    }
  }
  __syncthreads();

  // ---- K-loop ----
  const int lane = tid & 63;
  const int w = tid >> 6;
  const int bw = w & 1;
  const int kw = w >> 1;
  constexpr int KCH = KRANGE / 4;
  const int col = bx * 64 + lane;
  const float* Wp = W + (size_t)(by * KRANGE + kw * KCH) * N + col;
  const int fbase = ((SRC == SRC_LN) ? by * KRANGE : 0) + kw * KCH;
  float acc[8];
#pragma unroll
  for (int i = 0; i < 8; ++i) acc[i] = 0.f;
  for (int k = 0; k < KCH; k += 8) {
    float wv[8];
#pragma unroll
    for (int u = 0; u < 8; ++u) wv[u] = Wp[(size_t)(k + u) * N];
#pragma unroll
    for (int u = 0; u < 8; ++u) {
      const float4* a4 = (const float4*)&sm[(fbase + k + u) * BATCH + bw * 8];
      float4 A0 = a4[0], A1 = a4[1];
      acc[0] = fmaf(A0.x, wv[u], acc[0]);
      acc[1] = fmaf(A0.y, wv[u], acc[1]);
      acc[2] = fmaf(A0.z, wv[u], acc[2]);
      acc[3] = fmaf(A0.w, wv[u], acc[3]);
      acc[4] = fmaf(A1.x, wv[u], acc[4]);
      acc[5] = fmaf(A1.y, wv[u], acc[5]);
      acc[6] = fmaf(A1.z, wv[u], acc[6]);
      acc[7] = fmaf(A1.w, wv[u], acc[7]);
    }
  }
  __syncthreads();
#pragma unroll
  for (int i = 0; i < 8; ++i) sm[(w * 8 + i) * 64 + lane] = acc[i];
  __syncthreads();
  for (int o = tid; o < BATCH * 64; o += 512) {
    int b, gn_l;
    if (LAYOUT == 1) {
      b = o & 15;
      gn_l = o >> 4;
    } else {
      b = o >> 6;
      gn_l = o & 63;
    }
    int bw2 = b >> 3, bi = b & 7;
    float v = 0.f;
#pragma unroll
    for (int k2 = 0; k2 < 4; ++k2) v += sm[(((k2 * 2 + bw2) * 8) + bi) * 64 + gn_l];
    int gn = bx * 64 + gn_l;
    if (BIAS && by == 0) v += bias[gn];
    if (KB == 1 && LAYOUT == 0)
      out[(size_t)b * N + gn] = v;
    else if (LAYOUT == 0)
      out[((size_t)by * BATCH + b) * N + gn] = v;
    else
      out[(size_t)by * N * BATCH + (size_t)gn * BATCH + b] = v;
  }
}

// ---------------- decode attention stage (8 waves/block, wave = one (b,h)) ----------------
__device__ __forceinline__ void attn_stage(SmAttn& S, int blk, const float* __restrict__ qp,
                                           const int* __restrict__ lens, float* __restrict__ kcT,
                                           float* __restrict__ vc, float* __restrict__ ot) {
  const int tid = threadIdx.x;
  const int d = tid & 63;
  const int wv = tid >> 6;
  const int bh = blk * 8 + wv;  // = b*NHEAD + h
  const int h = bh % NHEAD, b = bh / NHEAD;
  int p = lens[b] - 1;
  if (p < 0) p = 0;
  if (p > TMAX - 1) p = TMAX - 1;
  const float* q0 = qp + (size_t)b * 3 * DIM + h * HEADD;
  const float* q1 = qp + (size_t)BATCH * 3 * DIM + (size_t)b * 3 * DIM + h * HEADD;
  float qv = q0[d] + q1[d];
  float kself = q0[DIM + d] + q1[DIM + d];
  float vself = q0[2 * DIM + d] + q1[2 * DIM + d];
  float* kT = kcT + (size_t)bh * HEADD * TMAX;  // [64][80]
  float* vb = vc + (size_t)bh * TMAX * HEADD;   // [80][64]
  kT[d * TMAX + p] = kself;
  vb[p * HEADD + d] = vself;
  float* qs = S.qs[wv];
  float* ps = S.ps[wv];
  qs[d] = qv;
  __syncthreads();
  float pd = qv * kself;
  for (int off = 32; off > 0; off >>= 1) pd += __shfl_xor(pd, off);
  float selfdot = pd * ATT_SCALE;
  float s0 = -1e30f, s1 = -1e30f;
  int t1 = d + 64;
  if (d < p) {
    float a = 0.f;
    for (int dd = 0; dd < HEADD; ++dd) a += qs[dd] * kT[dd * TMAX + d];
    s0 = a * ATT_SCALE;
  } else if (d == p) {
    s0 = selfdot;
  }
  if (t1 < p) {
    float a = 0.f;
    for (int dd = 0; dd < HEADD; ++dd) a += qs[dd] * kT[dd * TMAX + t1];
    s1 = a * ATT_SCALE;
  } else if (t1 == p) {
    s1 = selfdot;
  }
  float mx = fmaxf(s0, s1);
  for (int off = 32; off > 0; off >>= 1) mx = fmaxf(mx, __shfl_xor(mx, off));
  float e0 = (d <= p) ? expf(s0 - mx) : 0.f;
  float e1 = (t1 <= p) ? expf(s1 - mx) : 0.f;
  float sum = e0 + e1;
  for (int off = 32; off > 0; off >>= 1) sum += __shfl_xor(sum, off);
  float inv = 1.f / sum;
  ps[d] = e0 * inv;
  if (d < TMAX - 64) ps[t1] = e1 * inv;
  __syncthreads();
  float acc = 0.f;
  for (int t = 0; t < p; ++t) acc += ps[t] * vb[t * HEADD + d];
  acc += ps[p] * vself;
  ot[(size_t)(h * HEADD + d) * BATCH + b] = acc;
}

// ---------------- decode update stage (512 threads, block = one batch) ----------------
__device__ __forceinline__ void update_stage(SmUpd& S, int b, const float* __restrict__ logits,
                                             int* ids, int* lens, int* fin, float* csum,
                                             float* ccnt, float* out_gen, int step,
                                             const float* __restrict__ wte,
                                             const float* __restrict__ wpe, float* xdT) {
  const int tid = threadIdx.x;
  const float* lr = logits + (size_t)b * VOCAB;
  float best = -1e30f;
  int besti = 0;
  for (int i = tid; i < VOCAB; i += 512) {
    float v = lr[i];
    if (v > best) {
      best = v;
      besti = i;
    }
  }
  S.vred[tid] = best;
  S.ired[tid] = besti;
  __syncthreads();
  for (int s = 256; s > 0; s >>= 1) {
    if (tid < s) {
      if (S.vred[tid + s] > S.vred[tid] ||
          (S.vred[tid + s] == S.vred[tid] && S.ired[tid + s] < S.ired[tid])) {
        S.vred[tid] = S.vred[tid + s];
        S.ired[tid] = S.ired[tid + s];
      }
    }
    __syncthreads();
  }
  float mx = S.vred[0];
  int top = S.ired[0];
  __syncthreads();
  float se = 0.f;
  for (int i = tid; i < VOCAB; i += 512) se += expf(lr[i] - mx);
  S.vred[tid] = se;
  __syncthreads();
  for (int s = 256; s > 0; s >>= 1) {
    if (tid < s) S.vred[tid] += S.vred[tid + s];
    __syncthreads();
  }
  if (tid == 0) {
    float top_p = 1.f / S.vred[0];
    int l = lens[b];
    bool active = (!fin[b]) && (l < TMAX);
    if (active) {
      csum[b] += top_p;
      ccnt[b] += 1.f;
    }
    bool is_end = (top == 3) || (top == 0);
    bool wr = active && !is_end;
    if (wr) {
      ids[b * TMAX + l] = top;
      lens[b] = l + 1;
    }
    if (active && is_end) fin[b] = 1;
    out_gen[b * NNEW + step] = wr ? (float)top : 0.f;
    int l2 = lens[b];
    int pn = l2 - 1;
    if (pn < 0) pn = 0;
    if (pn > TMAX - 1) pn = TMAX - 1;
    S.sh_pos = pn;
    S.sh_tok = ids[b * TMAX + pn];
  }
  __syncthreads();
  int tok = S.sh_tok, pn = S.sh_pos;
  xdT[(size_t)tid * BATCH + b] = wte[(size_t)tok * DIM + tid] + wpe[(size_t)pn * DIM + tid];
}

struct DecArgs {
  const float *wte, *wpe, *ln1_w, *ln1_b, *qkv_w, *qkv_b, *ao_w, *ao_b, *ln2_w, *ln2_b;
  const float *fc_w, *fc_b, *pr_w, *pr_b, *lnf_w, *lnf_b, *lm_w;
  int *ids, *lens, *fin;
  float *csum, *ccnt;
  float *kc, *vc;
  float *xd0, *xd1, *ot, *qkp, *aop, *fcp, *prp, *logits;
  float* out;
  unsigned* flags;
};

__global__ __launch_bounds__(512) void k_decode(DecArgs a) {
  __shared__ SmAll sm;
  const int blk = blockIdx.x;
  const int tid = threadIdx.x;
  const size_t kvstride = (size_t)BATCH * NHEAD * TMAX * HEADD;
  unsigned gen = 0;

  // embed0: xd0[d][b] = wte[tok] + wpe[pos]
  if (blk < BATCH) {
    int b = blk;
    int p = a.lens[b] - 1;
    if (p < 0) p = 0;
    if (p > TMAX - 1) p = TMAX - 1;
    int tok = a.ids[b * TMAX + p];
    a.xd0[(size_t)tid * BATCH + b] = a.wte[(size_t)tok * DIM + tid] + a.wpe[(size_t)p * DIM + tid];
  }
  gsync(a.flags, ++gen);

  for (int s = 0; s < NNEW; ++s) {
    for (int l = 0; l < NLAYER; ++l) {
      float* kc = a.kc + (size_t)l * kvstride;
      float* vc = a.vc + (size_t)l * kvstride;
      // QKV: ln1(xd) @ qkv_w -> 2 row-major partials [2][16][1536]
      if (blk < 48) {
        if (l == 0)
          skinny_stage<2, SRC_LN, 0, 0, true, false, 3 * DIM, DIM>(
              sm.g, blk % 24, blk / 24, a.xd0, nullptr, a.ln1_w + l * DIM, a.ln1_b + l * DIM,
              a.qkv_b + (size_t)l * 3 * DIM, a.qkv_w + (size_t)l * DIM * 3 * DIM, a.qkp, nullptr);
        else
          skinny_stage<2, SRC_LN, 4, 0, true, true, 3 * DIM, DIM>(
              sm.g, blk % 24, blk / 24, a.xd1, a.prp, a.ln1_w + l * DIM, a.ln1_b + l * DIM,
              a.qkv_b + (size_t)l * 3 * DIM, a.qkv_w + (size_t)l * DIM * 3 * DIM, a.qkp, a.xd0);
      }
      gsync(a.flags, ++gen);
      // attention: sums 2 qkv partials, appends KV, Ot[512][16]
      if (blk < 16) attn_stage(sm.a, blk, a.qkp, a.lens, kc, vc, a.ot);
      gsync(a.flags, ++gen);
      // AO: Ot @ ao_w -> 2 transposed partials [2][512][16]
      if (blk < 16)
        skinny_stage<2, SRC_PLAIN, 0, 1, true, false, DIM, DIM>(
            sm.g, blk % 8, blk / 8, a.ot, nullptr, nullptr, nullptr, a.ao_b + (size_t)l * DIM,
            a.ao_w + (size_t)l * DIM * DIM, a.aop, nullptr);
      gsync(a.flags, ++gen);
      // FC: ln2(xd0 + 2 ao partials) @ fc_w -> 2 transposed partials; write xd1
      if (blk < 64)
        skinny_stage<2, SRC_LN, 2, 1, true, true, 4 * DIM, DIM>(
            sm.g, blk % 32, blk / 32, a.xd0, a.aop, a.ln2_w + l * DIM, a.ln2_b + l * DIM,
            a.fc_b + (size_t)l * 4 * DIM, a.fc_w + (size_t)l * DIM * 4 * DIM, a.fcp, a.xd1);
      gsync(a.flags, ++gen);
      // PR: gelu(sum 2 fc partials) @ pr_w -> 4 transposed partials [4][512][16]
      if (blk < 32)
        skinny_stage<4, SRC_GELU, 2, 1, true, false, DIM, 4 * DIM>(
            sm.g, blk % 8, blk / 8, nullptr, a.fcp, nullptr, nullptr, a.pr_b + (size_t)l * DIM,
            a.pr_w + (size_t)l * 4 * DIM * DIM, a.prp, nullptr);
      gsync(a.flags, ++gen);
    }
    // logits = lnf(xd1 + 4 pr partials)^T @ lm_w  (lnf fused into the SRC_LN staging)
    if (blk < VOCAB / 64)
      skinny_stage<1, SRC_LN, 4, 0, false, false, VOCAB, DIM>(
          sm.g, blk, 0, a.xd1, a.prp, a.lnf_w, a.lnf_b, nullptr, a.lm_w, a.logits, nullptr);
    gsync(a.flags, ++gen);
    // update state + embed next token -> xd0
    if (blk < BATCH)
      update_stage(sm.u, blk, a.logits, a.ids, a.lens, a.fin, a.csum, a.ccnt, a.out, s, a.wte,
                   a.wpe, a.xd0);
    gsync(a.flags, ++gen);
  }
  // finalize confidences
  if (blk == 0 && tid < BATCH) a.out[BATCH * NNEW + tid] = a.csum[tid] / fmaxf(a.ccnt[tid], 1.f);
}

// ---------------- host launch ----------------
extern "C" void kernel_launch(void* const* d_in, const int* in_sizes, int n_in, void* d_out,
                              int out_size, void* d_ws, size_t ws_size, hipStream_t stream) {
  const float* wte = (const float*)d_in[0];
  const float* wpe = (const float*)d_in[1];
  const float* ln1_w = (const float*)d_in[2];
  const float* ln1_b = (const float*)d_in[3];
  const float* qkv_w = (const float*)d_in[4];
  const float* qkv_b = (const float*)d_in[5];
  const float* ao_w = (const float*)d_in[6];
  const float* ao_b = (const float*)d_in[7];
  const float* ln2_w = (const float*)d_in[8];
  const float* ln2_b = (const float*)d_in[9];
  const float* fc_w = (const float*)d_in[10];
  const float* fc_b = (const float*)d_in[11];
  const float* pr_w = (const float*)d_in[12];
  const float* pr_b = (const float*)d_in[13];
  const float* lnf_w = (const float*)d_in[14];
  const float* lnf_b = (const float*)d_in[15];
  const float* lm_w = (const float*)d_in[16];
  const int* ids_in = (const int*)d_in[17];
  const int* mask_in = (const int*)d_in[18];
  float* out = (float*)d_out;

  char* p = (char*)d_ws;
  auto carve = [&](size_t nbytes) {
    char* r = p;
    p += (nbytes + 255) & ~(size_t)255;
    return (void*)r;
  };
  int* w_ids = (int*)carve(BATCH * TMAX * 4);
  int* w_lens = (int*)carve(BATCH * 4);
  int* w_fin = (int*)carve(BATCH * 4);
  float* w_csum = (float*)carve(BATCH * 4);
  float* w_ccnt = (float*)carve(BATCH * 4);
  float* w_x = (float*)carve((size_t)BATCH * PROMPT_LEN * DIM * 4);
  float* w_h = (float*)carve((size_t)BATCH * PROMPT_LEN * DIM * 4);
  float* w_qkv = (float*)carve((size_t)BATCH * PROMPT_LEN * 3 * DIM * 4);
  float* w_att = (float*)carve((size_t)BATCH * PROMPT_LEN * DIM * 4);
  float* w_mlp = (float*)carve((size_t)BATCH * PROMPT_LEN * 4 * DIM * 4);
  float* w_kc = (float*)carve((size_t)NLAYER * BATCH * NHEAD * TMAX * HEADD * 4);
  float* w_vc = (float*)carve((size_t)NLAYER * BATCH * NHEAD * TMAX * HEADD * 4);
  float* w_xd0 = (float*)carve((size_t)DIM * BATCH * 4);
  float* w_xd1 = (float*)carve((size_t)DIM * BATCH * 4);
  float* w_ot = (float*)carve((size_t)DIM * BATCH * 4);
  float* w_qkp = (float*)carve((size_t)2 * BATCH * 3 * DIM * 4);
  float* w_aop = (float*)carve((size_t)2 * DIM * BATCH * 4);
  float* w_fcp = (float*)carve((size_t)2 * 4 * DIM * BATCH * 4);
  float* w_prp = (float*)carve((size_t)4 * DIM * BATCH * 4);
  float* w_logits = (float*)carve((size_t)BATCH * VOCAB * 4);
  unsigned* w_flags = (unsigned*)carve((size_t)GRIDN * FLAG_STRIDE * 4);

  const int M = BATCH * PROMPT_LEN;  // 1024
  const size_t kvstride = (size_t)BATCH * NHEAD * TMAX * HEADD;

  k_init<<<1, 256, 0, stream>>>(ids_in, mask_in, w_ids, w_lens, w_fin, w_csum, w_ccnt, w_flags);
  k_embed_prefill<<<M, 256, 0, stream>>>(w_ids, wte, wpe, w_x);

  for (int l = 0; l < NLAYER; ++l) {
    float* kc = w_kc + (size_t)l * kvstride;
    float* vc = w_vc + (size_t)l * kvstride;
    k_layernorm<<<M, 256, 0, stream>>>(w_x, ln1_w + l * DIM, ln1_b + l * DIM, w_h);
    gemm_kernel<3><<<dim3(3 * DIM / 64, M / 64), 256, 0, stream>>>(
        w_h, qkv_w + (size_t)l * DIM * 3 * DIM, qkv_b + (size_t)l * 3 * DIM, nullptr, w_qkv, M,
        3 * DIM, DIM, kc, vc);
    k_attn_prefill<<<BATCH * NHEAD * PROMPT_LEN, 64, 0, stream>>>(w_qkv, kc, vc, w_att);
    gemm_kernel<2><<<dim3(DIM / 64, M / 64), 256, 0, stream>>>(
        w_att, ao_w + (size_t)l * DIM * DIM, ao_b + (size_t)l * DIM, w_x, w_x, M, DIM, DIM,
        nullptr, nullptr);
    k_layernorm<<<M, 256, 0, stream>>>(w_x, ln2_w + l * DIM, ln2_b + l * DIM, w_h);
    gemm_kernel<1><<<dim3(4 * DIM / 64, M / 64), 256, 0, stream>>>(
        w_h, fc_w + (size_t)l * DIM * 4 * DIM, fc_b + (size_t)l * 4 * DIM, nullptr, w_mlp, M,
        4 * DIM, DIM, nullptr, nullptr);
    gemm_kernel<2><<<dim3(DIM / 64, M / 64), 256, 0, stream>>>(
        w_mlp, pr_w + (size_t)l * 4 * DIM * DIM, pr_b + (size_t)l * DIM, w_x, w_x, M, DIM,
        4 * DIM, nullptr, nullptr);
  }

  // ---- persistent decode: one kernel, internal grid barriers ----
  DecArgs da;
  da.wte = wte;
  da.wpe = wpe;
  da.ln1_w = ln1_w;
  da.ln1_b = ln1_b;
  da.qkv_w = qkv_w;
  da.qkv_b = qkv_b;
  da.ao_w = ao_w;
  da.ao_b = ao_b;
  da.ln2_w = ln2_w;
  da.ln2_b = ln2_b;
  da.fc_w = fc_w;
  da.fc_b = fc_b;
  da.pr_w = pr_w;
  da.pr_b = pr_b;
  da.lnf_w = lnf_w;
  da.lnf_b = lnf_b;
  da.lm_w = lm_w;
  da.ids = w_ids;
  da.lens = w_lens;
  da.fin = w_fin;
  da.csum = w_csum;
  da.ccnt = w_ccnt;
  da.kc = w_kc;
  da.vc = w_vc;
  da.xd0 = w_xd0;
  da.xd1 = w_xd1;
  da.ot = w_ot;
  da.qkp = w_qkp;
  da.aop = w_aop;
  da.fcp = w_fcp;
  da.prp = w_prp;
  da.logits = w_logits;
  da.out = out;
  da.flags = w_flags;
  k_decode<<<GRIDN, 512, 0, stream>>>(da);
}

// Round 5
// 22699.054 us; speedup vs baseline: 1.2525x; 1.2525x over previous
//
#include <hip/hip_runtime.h>
#include <math.h>

#define VOCAB 8000
#define DIM 512
#define NLAYER 8
#define NHEAD 8
#define BATCH 16
#define TMAX 80
#define PROMPT_LEN 64
#define NNEW 16
#define HEADD 64
#define ATT_SCALE 0.125f

#define SRC_PLAIN 0
#define SRC_LN 1
#define SRC_GELU 2

// persistent decode kernel grid: 64 blocks x 512 thr, ~34KB LDS. Trivially
// co-resident on 256 CUs (1 block/4 CUs). Block 0 is the barrier master.
#define GRIDN 64
// flag stride in u32 units: 128B per flag line to avoid false sharing
#define FSTRIDE 32

__device__ __forceinline__ float gelu_f(float x) {
  return 0.5f * x * (1.0f + tanhf(0.7978845608028654f * (x + 0.044715f * x * x * x)));
}

// ---------------- init ----------------
__global__ void k_init(const int* __restrict__ ids_in, const int* __restrict__ mask_in,
                       int* __restrict__ ids, int* __restrict__ lens, int* __restrict__ fin,
                       float* __restrict__ csum, float* __restrict__ ccnt,
                       unsigned* __restrict__ flags, unsigned* __restrict__ go) {
  int tid = threadIdx.x;
  for (int i = tid; i < BATCH * TMAX; i += blockDim.x) ids[i] = ids_in[i];
  // zero barrier state (graph replays reuse the workspace)
  for (int i = tid; i < GRIDN * FSTRIDE; i += blockDim.x) flags[i] = 0u;
  if (tid == 0) *go = 0u;
  if (tid < BATCH) {
    int s = 0;
    for (int t = 0; t < TMAX; ++t) s += mask_in[tid * TMAX + t];
    lens[tid] = s;
    fin[tid] = 0;
    csum[tid] = 0.f;
    ccnt[tid] = 0.f;
  }
}

// ---------------- prefill embedding ----------------
__global__ void k_embed_prefill(const int* __restrict__ ids, const float* __restrict__ wte,
                                const float* __restrict__ wpe, float* __restrict__ x) {
  int bt = blockIdx.x;
  int b = bt / PROMPT_LEN, t = bt % PROMPT_LEN;
  int tok = ids[b * TMAX + t];
  for (int d = threadIdx.x; d < DIM; d += blockDim.x)
    x[(size_t)bt * DIM + d] = wte[(size_t)tok * DIM + d] + wpe[(size_t)t * DIM + d];
}

// ---------------- prefill layernorm ----------------
__global__ void k_layernorm(const float* __restrict__ x, const float* __restrict__ w,
                            const float* __restrict__ b, float* __restrict__ out) {
  int row = blockIdx.x;
  int tid = threadIdx.x;
  const float* xr = x + (size_t)row * DIM;
  __shared__ float red[256];
  float v0 = xr[tid], v1 = xr[tid + 256];
  red[tid] = v0 + v1;
  __syncthreads();
  for (int s = 128; s > 0; s >>= 1) {
    if (tid < s) red[tid] += red[tid + s];
    __syncthreads();
  }
  float mean = red[0] * (1.0f / DIM);
  __syncthreads();
  float d0 = v0 - mean, d1 = v1 - mean;
  red[tid] = d0 * d0 + d1 * d1;
  __syncthreads();
  for (int s = 128; s > 0; s >>= 1) {
    if (tid < s) red[tid] += red[tid + s];
    __syncthreads();
  }
  float rstd = 1.0f / sqrtf(red[0] * (1.0f / DIM) + 1e-5f);
  out[(size_t)row * DIM + tid] = d0 * rstd * w[tid] + b[tid];
  out[(size_t)row * DIM + tid + 256] = d1 * rstd * w[tid + 256] + b[tid + 256];
}

// ---------------- prefill tiled GEMM ----------------
// MODE: 1 = gelu(+bias), 2 = +bias +res, 3 = qkv epilogue (+bias, write q + KV caches)
template <int MODE>
__global__ __launch_bounds__(256) void gemm_kernel(const float* __restrict__ A,
                                                   const float* __restrict__ W,
                                                   const float* __restrict__ bias,
                                                   const float* __restrict__ res,
                                                   float* __restrict__ C, int M, int N, int K,
                                                   float* __restrict__ kcT,
                                                   float* __restrict__ vc) {
  const int BM = 64, BN = 64, BK = 16;
  __shared__ float As[BK][BM + 4];
  __shared__ float Ws[BK][BN];
  int tid = threadIdx.x;
  int bm = blockIdx.y * BM, bn = blockIdx.x * BN;
  int tr = tid / 16, tc = tid % 16;
  float acc[4][4];
#pragma unroll
  for (int i = 0; i < 4; i++)
#pragma unroll
    for (int j = 0; j < 4; j++) acc[i][j] = 0.f;

  for (int k0 = 0; k0 < K; k0 += BK) {
    for (int i = tid; i < BM * BK; i += 256) {
      int m = i / BK, kk = i % BK;
      As[kk][m] = A[(size_t)(bm + m) * K + k0 + kk];
    }
    for (int i = tid; i < BK * BN; i += 256) {
      int kk = i / BN, n = i % BN;
      Ws[kk][n] = W[(size_t)(k0 + kk) * N + bn + n];
    }
    __syncthreads();
#pragma unroll
    for (int kk = 0; kk < BK; ++kk) {
      float a[4], w[4];
#pragma unroll
      for (int i = 0; i < 4; i++) a[i] = As[kk][tr * 4 + i];
#pragma unroll
      for (int j = 0; j < 4; j++) w[j] = Ws[kk][tc * 4 + j];
#pragma unroll
      for (int i = 0; i < 4; i++)
#pragma unroll
        for (int j = 0; j < 4; j++) acc[i][j] += a[i] * w[j];
    }
    __syncthreads();
  }
#pragma unroll
  for (int i = 0; i < 4; i++) {
    int m = bm + tr * 4 + i;
#pragma unroll
    for (int j = 0; j < 4; j++) {
      int n = bn + tc * 4 + j;
      float v = acc[i][j] + (bias ? bias[n] : 0.f);
      if (MODE == 1) v = gelu_f(v);
      if (MODE == 2) v += res[(size_t)m * N + n];
      if (MODE == 3) {
        int b = m >> 6, t = m & 63;
        if (n < DIM) {
          C[(size_t)m * N + n] = v;  // q (only q region consumed)
        } else if (n < 2 * DIM) {
          int dd = n - DIM;
          kcT[((size_t)(b * NHEAD + (dd >> 6)) * HEADD + (dd & 63)) * TMAX + t] = v;
        } else {
          int dd = n - 2 * DIM;
          vc[((size_t)(b * NHEAD + (dd >> 6)) * TMAX + t) * HEADD + (dd & 63)] = v;
        }
      } else {
        C[(size_t)m * N + n] = v;
      }
    }
  }
}

// ---------------- prefill attention (K^T cache layout) ----------------
__global__ void k_attn_prefill(const float* __restrict__ qkv, const float* __restrict__ kcT,
                               const float* __restrict__ vc, float* __restrict__ o) {
  int blk = blockIdx.x;
  int q = blk % PROMPT_LEN;
  int bh = blk / PROMPT_LEN;
  int h = bh % NHEAD, b = bh / NHEAD;
  int tid = threadIdx.x;  // 64
  __shared__ float qs[HEADD];
  __shared__ float ps[PROMPT_LEN];
  qs[tid] = qkv[(size_t)(b * PROMPT_LEN + q) * 3 * DIM + h * HEADD + tid];
  __syncthreads();
  const float* kbT = kcT + (size_t)(b * NHEAD + h) * HEADD * TMAX;  // [64][80]
  const float* vb = vc + (size_t)(b * NHEAD + h) * TMAX * HEADD;    // [80][64]
  float s = -1e30f;
  if (tid <= q) {
    float a = 0.f;
    for (int d = 0; d < HEADD; ++d) a += qs[d] * kbT[d * TMAX + tid];
    s = a * ATT_SCALE;
  }
  float mx = s;
  for (int off = 32; off > 0; off >>= 1) mx = fmaxf(mx, __shfl_xor(mx, off));
  float e = (tid <= q) ? expf(s - mx) : 0.f;
  float sum = e;
  for (int off = 32; off > 0; off >>= 1) sum += __shfl_xor(sum, off);
  ps[tid] = e / sum;
  __syncthreads();
  float acc = 0.f;
  for (int t = 0; t <= q; ++t) acc += ps[t] * vb[t * HEADD + tid];
  o[(size_t)(b * PROMPT_LEN + q) * DIM + h * HEADD + tid] = acc;
}

// ================= persistent decode kernel =================

struct SmGemm {
  float sm[DIM * BATCH];  // 8192 floats, max SROWS*BATCH over all stages
  float wsum[8][BATCH];
  float wss[8][BATCH];
  float smean[BATCH], srstd[BATCH];
};
struct SmAttn {
  float qs[8][HEADD];
  float ps[8][TMAX];
};
struct SmUpd {
  float vred[512];
  int ired[512];
  int sh_tok, sh_pos;
};
union SmAll {
  SmGemm g;
  SmAttn a;
  SmUpd u;
};

// Grid barrier, master-broadcast form:
//  arrive:   each block store-releases `gen` to its OWN 128B-spaced flag
//            (concurrent plain stores — no RMW serialization, unlike r1's 24us)
//  detect:   master wave (block 0, lanes 0..63): lane i polls flag i — all 64
//            flags checked by ONE vector load per poll round
//  release:  master store-releases `gen` to the single `go` word; every block
//            polls `go` with one thread (read-shared line, one inval per phase)
// Cost ~= 2 cross-device round-trips, vs 128 serialized RMWs (r1) or 16K
// pollers (r2).
__device__ __forceinline__ void gsync(unsigned* __restrict__ flags, unsigned* __restrict__ go,
                                      unsigned gen) {
  __syncthreads();
  if (threadIdx.x == 0)
    __hip_atomic_store(&flags[(unsigned)blockIdx.x * FSTRIDE], gen, __ATOMIC_RELEASE,
                       __HIP_MEMORY_SCOPE_AGENT);
  if (blockIdx.x == 0) {
    if (threadIdx.x < GRIDN) {  // one wave: lanes 0..63 poll flags 0..63
      while (__hip_atomic_load(&flags[threadIdx.x * FSTRIDE], __ATOMIC_RELAXED,
                               __HIP_MEMORY_SCOPE_AGENT) < gen)
        __builtin_amdgcn_s_sleep(1);
    }
    // wave reconverged: all 64 arrivals observed
    if (threadIdx.x == 0) {
      __threadfence();  // order flag observations before go release
      __hip_atomic_store(go, gen, __ATOMIC_RELEASE, __HIP_MEMORY_SCOPE_AGENT);
    }
  }
  if (threadIdx.x == 0) {
    while (__hip_atomic_load(go, __ATOMIC_RELAXED, __HIP_MEMORY_SCOPE_AGENT) < gen)
      __builtin_amdgcn_s_sleep(1);
  }
  __threadfence();  // acquire: make remote data visible to this CU
  __syncthreads();
}

// ---------------- decode skinny GEMM stage (device fn; 512 threads) ----------------
// C[16,N] = A^T[16,K] @ W[K,N]. A ([K][16]) is built in LDS from:
//   SRC_PLAIN: src            SRC_LN: ln(src + sum parts) (full-K stage; opt. write xd)
//   SRC_GELU: gelu(sum parts)
// 8 waves = 2 batch-groups x 4 k-chunks. KB = cross-block split-K (partials out,
// bias folded into partial kb==0). LAYOUT: 0 row-major [kb][16][N], 1 transposed [kb][N][16].
template <int KB, int SRC, int P, int LAYOUT, bool BIAS, bool XDW, int N, int K>
__device__ __forceinline__ void skinny_stage(SmGemm& S, int bx, int by,
                                             const float* __restrict__ src,
                                             const float* __restrict__ parts,
                                             const float* __restrict__ lnw,
                                             const float* __restrict__ lnb,
                                             const float* __restrict__ bias,
                                             const float* __restrict__ W, float* __restrict__ out,
                                             float* __restrict__ xdout) {
  constexpr int KRANGE = K / KB;
  constexpr int SROWS = (SRC == SRC_LN) ? K : KRANGE;
  float* sm = S.sm;
  const int tid = threadIdx.x;
  const int base_row = (SRC == SRC_LN) ? 0 : by * KRANGE;

  // ---- stage ----
  {
    const float4* s4 = (const float4*)src;
    float4* d4 = (float4*)sm;
    constexpr int NF4 = SROWS * BATCH / 4;
    for (int i = tid; i < NF4; i += 512) {
      int gi = base_row * (BATCH / 4) + i;
      float4 v;
      if (SRC == SRC_GELU) {
        v = make_float4(0.f, 0.f, 0.f, 0.f);
      } else {
        v = s4[gi];
      }
#pragma unroll
      for (int p = 0; p < P; ++p) {
        const float4* p4 = (const float4*)(parts + (size_t)p * K * BATCH);
        float4 t = p4[gi];
        v.x += t.x;
        v.y += t.y;
        v.z += t.z;
        v.w += t.w;
      }
      if (SRC == SRC_GELU) {
        v.x = gelu_f(v.x);
        v.y = gelu_f(v.y);
        v.z = gelu_f(v.z);
        v.w = gelu_f(v.w);
      }
      if (XDW) {
        if (bx == 0 && by == 0) ((float4*)xdout)[gi] = v;
      }
      d4[i] = v;
    }
  }
  if (SRC == SRC_LN) {
    __syncthreads();
    float s = 0.f, ss = 0.f;
#pragma unroll
    for (int j = 0; j < 16; ++j) {
      float v = sm[tid + 512 * j];
      s += v;
      ss += v * v;
    }
    s += __shfl_xor(s, 16);
    ss += __shfl_xor(ss, 16);
    s += __shfl_xor(s, 32);
    ss += __shfl_xor(ss, 32);
    int lane0 = tid & 63, w0 = tid >> 6;
    if (lane0 < BATCH) {
      S.wsum[w0][lane0] = s;
      S.wss[w0][lane0] = ss;
    }
    __syncthreads();
    if (tid < BATCH) {
      float ts = 0.f, tss = 0.f;
#pragma unroll
      for (int ww = 0; ww < 8; ++ww) {
        ts += S.wsum[ww][tid];
        tss += S.wss[ww][tid];
      }
      float m = ts * (1.0f / K);
      float var = tss * (1.0f / K) - m * m;
      S.smean[tid] = m;
      S.srstd[tid] = 1.0f / sqrtf(var + 1e-5f);
    }
    __syncthreads();
    float mb = S.smean[tid & 15];
    float rb = S.srstd[tid & 15];
#pragma unroll
    for (int j = 0; j < 16; ++j) {
      int idx = tid + 512 * j;
      int k = idx >> 4;
      sm[idx] = (sm[idx] - mb) * rb * lnw[k] + lnb[k];
    }
  }
  __syncthreads();

  // ---- K-loop ----
  const int lane = tid & 63;
  const int w = tid >> 6;
  const int bw = w & 1;
  const int kw = w >> 1;
  constexpr int KCH = KRANGE / 4;
  const int col = bx * 64 + lane;
  const float* Wp = W + (size_t)(by * KRANGE + kw * KCH) * N + col;
  const int fbase = ((SRC == SRC_LN) ? by * KRANGE : 0) + kw * KCH;
  float acc[8];
#pragma unroll
  for (int i = 0; i < 8; ++i) acc[i] = 0.f;
  for (int k = 0; k < KCH; k += 8) {
    float wv[8];
#pragma unroll
    for (int u = 0; u < 8; ++u) wv[u] = Wp[(size_t)(k + u) * N];
#pragma unroll
    for (int u = 0; u < 8; ++u) {
      const float4* a4 = (const float4*)&sm[(fbase + k + u) * BATCH + bw * 8];
      float4 A0 = a4[0], A1 = a4[1];
      acc[0] = fmaf(A0.x, wv[u], acc[0]);
      acc[1] = fmaf(A0.y, wv[u], acc[1]);
      acc[2] = fmaf(A0.z, wv[u], acc[2]);
      acc[3] = fmaf(A0.w, wv[u], acc[3]);
      acc[4] = fmaf(A1.x, wv[u], acc[4]);
      acc[5] = fmaf(A1.y, wv[u], acc[5]);
      acc[6] = fmaf(A1.z, wv[u], acc[6]);
      acc[7] = fmaf(A1.w, wv[u], acc[7]);
    }
  }
  __syncthreads();
#pragma unroll
  for (int i = 0; i < 8; ++i) sm[(w * 8 + i) * 64 + lane] = acc[i];
  __syncthreads();
  for (int o = tid; o < BATCH * 64; o += 512) {
    int b, gn_l;
    if (LAYOUT == 1) {
      b = o & 15;
      gn_l = o >> 4;
    } else {
      b = o >> 6;
      gn_l = o & 63;
    }
    int bw2 = b >> 3, bi = b & 7;
    float v = 0.f;
#pragma unroll
    for (int k2 = 0; k2 < 4; ++k2) v += sm[(((k2 * 2 + bw2) * 8) + bi) * 64 + gn_l];
    int gn = bx * 64 + gn_l;
    if (BIAS && by == 0) v += bias[gn];
    if (KB == 1 && LAYOUT == 0)
      out[(size_t)b * N + gn] = v;
    else if (LAYOUT == 0)
      out[((size_t)by * BATCH + b) * N + gn] = v;
    else
      out[(size_t)by * N * BATCH + (size_t)gn * BATCH + b] = v;
  }
  // a block may run another virtual tile immediately after this one (e.g. the
  // 125-tile logits stage on 64 blocks): ensure all waves finished reading sm
  // before the next tile's staging overwrites it.
  __syncthreads();
}

// ---------------- decode attention stage (8 waves/block, wave = one (b,h)) ----------------
__device__ __forceinline__ void attn_stage(SmAttn& S, int blk, const float* __restrict__ qp,
                                           const int* __restrict__ lens, float* __restrict__ kcT,
                                           float* __restrict__ vc, float* __restrict__ ot) {
  const int tid = threadIdx.x;
  const int d = tid & 63;
  const int wv = tid >> 6;
  const int bh = blk * 8 + wv;  // = b*NHEAD + h
  const int h = bh % NHEAD, b = bh / NHEAD;
  int p = lens[b] - 1;
  if (p < 0) p = 0;
  if (p > TMAX - 1) p = TMAX - 1;
  const float* q0 = qp + (size_t)b * 3 * DIM + h * HEADD;
  const float* q1 = qp + (size_t)BATCH * 3 * DIM + (size_t)b * 3 * DIM + h * HEADD;
  float qv = q0[d] + q1[d];
  float kself = q0[DIM + d] + q1[DIM + d];
  float vself = q0[2 * DIM + d] + q1[2 * DIM + d];
  float* kT = kcT + (size_t)bh * HEADD * TMAX;  // [64][80]
  float* vb = vc + (size_t)bh * TMAX * HEADD;   // [80][64]
  kT[d * TMAX + p] = kself;
  vb[p * HEADD + d] = vself;
  float* qs = S.qs[wv];
  float* ps = S.ps[wv];
  qs[d] = qv;
  __syncthreads();
  float pd = qv * kself;
  for (int off = 32; off > 0; off >>= 1) pd += __shfl_xor(pd, off);
  float selfdot = pd * ATT_SCALE;
  float s0 = -1e30f, s1 = -1e30f;
  int t1 = d + 64;
  if (d < p) {
    float a = 0.f;
    for (int dd = 0; dd < HEADD; ++dd) a += qs[dd] * kT[dd * TMAX + d];
    s0 = a * ATT_SCALE;
  } else if (d == p) {
    s0 = selfdot;
  }
  if (t1 < p) {
    float a = 0.f;
    for (int dd = 0; dd < HEADD; ++dd) a += qs[dd] * kT[dd * TMAX + t1];
    s1 = a * ATT_SCALE;
  } else if (t1 == p) {
    s1 = selfdot;
  }
  float mx = fmaxf(s0, s1);
  for (int off = 32; off > 0; off >>= 1) mx = fmaxf(mx, __shfl_xor(mx, off));
  float e0 = (d <= p) ? expf(s0 - mx) : 0.f;
  float e1 = (t1 <= p) ? expf(s1 - mx) : 0.f;
  float sum = e0 + e1;
  for (int off = 32; off > 0; off >>= 1) sum += __shfl_xor(sum, off);
  float inv = 1.f / sum;
  ps[d] = e0 * inv;
  if (d < TMAX - 64) ps[t1] = e1 * inv;
  __syncthreads();
  float acc = 0.f;
  for (int t = 0; t < p; ++t) acc += ps[t] * vb[t * HEADD + d];
  acc += ps[p] * vself;
  ot[(size_t)(h * HEADD + d) * BATCH + b] = acc;
  __syncthreads();
}

// ---------------- decode update stage (512 threads, one batch element) ----------------
__device__ __forceinline__ void update_stage(SmUpd& S, int b, const float* __restrict__ logits,
                                             int* ids, int* lens, int* fin, float* csum,
                                             float* ccnt, float* out_gen, int step,
                                             const float* __restrict__ wte,
                                             const float* __restrict__ wpe, float* xdT) {
  const int tid = threadIdx.x;
  const float* lr = logits + (size_t)b * VOCAB;
  float best = -1e30f;
  int besti = 0;
  for (int i = tid; i < VOCAB; i += 512) {
    float v = lr[i];
    if (v > best) {
      best = v;
      besti = i;
    }
  }
  S.vred[tid] = best;
  S.ired[tid] = besti;
  __syncthreads();
  for (int s = 256; s > 0; s >>= 1) {
    if (tid < s) {
      if (S.vred[tid + s] > S.vred[tid] ||
          (S.vred[tid + s] == S.vred[tid] && S.ired[tid + s] < S.ired[tid])) {
        S.vred[tid] = S.vred[tid + s];
        S.ired[tid] = S.ired[tid + s];
      }
    }
    __syncthreads();
  }
  float mx = S.vred[0];
  int top = S.ired[0];
  __syncthreads();
  float se = 0.f;
  for (int i = tid; i < VOCAB; i += 512) se += expf(lr[i] - mx);
  S.vred[tid] = se;
  __syncthreads();
  for (int s = 256; s > 0; s >>= 1) {
    if (tid < s) S.vred[tid] += S.vred[tid + s];
    __syncthreads();
  }
  if (tid == 0) {
    float top_p = 1.f / S.vred[0];
    int l = lens[b];
    bool active = (!fin[b]) && (l < TMAX);
    if (active) {
      csum[b] += top_p;
      ccnt[b] += 1.f;
    }
    bool is_end = (top == 3) || (top == 0);
    bool wr = active && !is_end;
    if (wr) {
      ids[b * TMAX + l] = top;
      lens[b] = l + 1;
    }
    if (active && is_end) fin[b] = 1;
    out_gen[b * NNEW + step] = wr ? (float)top : 0.f;
    int l2 = lens[b];
    int pn = l2 - 1;
    if (pn < 0) pn = 0;
    if (pn > TMAX - 1) pn = TMAX - 1;
    S.sh_pos = pn;
    S.sh_tok = ids[b * TMAX + pn];
  }
  __syncthreads();
  int tok = S.sh_tok, pn = S.sh_pos;
  xdT[(size_t)tid * BATCH + b] = wte[(size_t)tok * DIM + tid] + wpe[(size_t)pn * DIM + tid];
  __syncthreads();
}

struct DecArgs {
  const float *wte, *wpe, *ln1_w, *ln1_b, *qkv_w, *qkv_b, *ao_w, *ao_b, *ln2_w, *ln2_b;
  const float *fc_w, *fc_b, *pr_w, *pr_b, *lnf_w, *lnf_b, *lm_w;
  int *ids, *lens, *fin;
  float *csum, *ccnt;
  float *kc, *vc;
  float *xd0, *xd1, *ot, *qkp, *aop, *fcp, *prp, *logits;
  float* out;
  unsigned *flags, *go;
};

__global__ __launch_bounds__(512) void k_decode(DecArgs a) {
  __shared__ SmAll sm;
  const int blk = blockIdx.x;
  const int tid = threadIdx.x;
  const size_t kvstride = (size_t)BATCH * NHEAD * TMAX * HEADD;
  unsigned gen = 0;

  // embed0: xd0[d][b] = wte[tok] + wpe[pos]
  if (blk < BATCH) {
    int b = blk;
    int p = a.lens[b] - 1;
    if (p < 0) p = 0;
    if (p > TMAX - 1) p = TMAX - 1;
    int tok = a.ids[b * TMAX + p];
    a.xd0[(size_t)tid * BATCH + b] = a.wte[(size_t)tok * DIM + tid] + a.wpe[(size_t)p * DIM + tid];
  }
  gsync(a.flags, a.go, ++gen);

  for (int s = 0; s < NNEW; ++s) {
    for (int l = 0; l < NLAYER; ++l) {
      float* kc = a.kc + (size_t)l * kvstride;
      float* vc = a.vc + (size_t)l * kvstride;
      // QKV: ln1(xd) @ qkv_w -> 2 row-major partials [2][16][1536]  (48 tiles)
      for (int vb = blk; vb < 48; vb += GRIDN) {
        if (l == 0)
          skinny_stage<2, SRC_LN, 0, 0, true, false, 3 * DIM, DIM>(
              sm.g, vb % 24, vb / 24, a.xd0, nullptr, a.ln1_w + l * DIM, a.ln1_b + l * DIM,
              a.qkv_b + (size_t)l * 3 * DIM, a.qkv_w + (size_t)l * DIM * 3 * DIM, a.qkp, nullptr);
        else
          skinny_stage<2, SRC_LN, 4, 0, true, true, 3 * DIM, DIM>(
              sm.g, vb % 24, vb / 24, a.xd1, a.prp, a.ln1_w + l * DIM, a.ln1_b + l * DIM,
              a.qkv_b + (size_t)l * 3 * DIM, a.qkv_w + (size_t)l * DIM * 3 * DIM, a.qkp, a.xd0);
      }
      gsync(a.flags, a.go, ++gen);
      // attention: sums 2 qkv partials, appends KV, Ot[512][16]  (16 tiles)
      for (int vb = blk; vb < 16; vb += GRIDN)
        attn_stage(sm.a, vb, a.qkp, a.lens, kc, vc, a.ot);
      gsync(a.flags, a.go, ++gen);
      // AO: Ot @ ao_w -> 2 transposed partials [2][512][16]  (16 tiles)
      for (int vb = blk; vb < 16; vb += GRIDN)
        skinny_stage<2, SRC_PLAIN, 0, 1, true, false, DIM, DIM>(
            sm.g, vb % 8, vb / 8, a.ot, nullptr, nullptr, nullptr, a.ao_b + (size_t)l * DIM,
            a.ao_w + (size_t)l * DIM * DIM, a.aop, nullptr);
      gsync(a.flags, a.go, ++gen);
      // FC: ln2(xd0 + 2 ao partials) @ fc_w -> 2 transposed partials; write xd1  (64 tiles)
      for (int vb = blk; vb < 64; vb += GRIDN)
        skinny_stage<2, SRC_LN, 2, 1, true, true, 4 * DIM, DIM>(
            sm.g, vb % 32, vb / 32, a.xd0, a.aop, a.ln2_w + l * DIM, a.ln2_b + l * DIM,
            a.fc_b + (size_t)l * 4 * DIM, a.fc_w + (size_t)l * DIM * 4 * DIM, a.fcp, a.xd1);
      gsync(a.flags, a.go, ++gen);
      // PR: gelu(sum 2 fc partials) @ pr_w -> 4 transposed partials [4][512][16]  (32 tiles)
      for (int vb = blk; vb < 32; vb += GRIDN)
        skinny_stage<4, SRC_GELU, 2, 1, true, false, DIM, 4 * DIM>(
            sm.g, vb % 8, vb / 8, nullptr, a.fcp, nullptr, nullptr, a.pr_b + (size_t)l * DIM,
            a.pr_w + (size_t)l * 4 * DIM * DIM, a.prp, nullptr);
      gsync(a.flags, a.go, ++gen);
    }
    // logits = lnf(xd1 + 4 pr partials)^T @ lm_w  (lnf fused; 125 tiles -> 2 rounds)
    for (int vb = blk; vb < VOCAB / 64; vb += GRIDN)
      skinny_stage<1, SRC_LN, 4, 0, false, false, VOCAB, DIM>(
          sm.g, vb, 0, a.xd1, a.prp, a.lnf_w, a.lnf_b, nullptr, a.lm_w, a.logits, nullptr);
    gsync(a.flags, a.go, ++gen);
    // update state + embed next token -> xd0  (16 tiles)
    for (int vb = blk; vb < BATCH; vb += GRIDN)
      update_stage(sm.u, vb, a.logits, a.ids, a.lens, a.fin, a.csum, a.ccnt, a.out, s, a.wte,
                   a.wpe, a.xd0);
    gsync(a.flags, a.go, ++gen);
  }
  // finalize confidences
  if (blk == 0 && tid < BATCH) a.out[BATCH * NNEW + tid] = a.csum[tid] / fmaxf(a.ccnt[tid], 1.f);
}

// ---------------- host launch ----------------
extern "C" void kernel_launch(void* const* d_in, const int* in_sizes, int n_in, void* d_out,
                              int out_size, void* d_ws, size_t ws_size, hipStream_t stream) {
  const float* wte = (const float*)d_in[0];
  const float* wpe = (const float*)d_in[1];
  const float* ln1_w = (const float*)d_in[2];
  const float* ln1_b = (const float*)d_in[3];
  const float* qkv_w = (const float*)d_in[4];
  const float* qkv_b = (const float*)d_in[5];
  const float* ao_w = (const float*)d_in[6];
  const float* ao_b = (const float*)d_in[7];
  const float* ln2_w = (const float*)d_in[8];
  const float* ln2_b = (const float*)d_in[9];
  const float* fc_w = (const float*)d_in[10];
  const float* fc_b = (const float*)d_in[11];
  const float* pr_w = (const float*)d_in[12];
  const float* pr_b = (const float*)d_in[13];
  const float* lnf_w = (const float*)d_in[14];
  const float* lnf_b = (const float*)d_in[15];
  const float* lm_w = (const float*)d_in[16];
  const int* ids_in = (const int*)d_in[17];
  const int* mask_in = (const int*)d_in[18];
  float* out = (float*)d_out;

  char* p = (char*)d_ws;
  auto carve = [&](size_t nbytes) {
    char* r = p;
    p += (nbytes + 255) & ~(size_t)255;
    return (void*)r;
  };
  int* w_ids = (int*)carve(BATCH * TMAX * 4);
  int* w_lens = (int*)carve(BATCH * 4);
  int* w_fin = (int*)carve(BATCH * 4);
  float* w_csum = (float*)carve(BATCH * 4);
  float* w_ccnt = (float*)carve(BATCH * 4);
  float* w_x = (float*)carve((size_t)BATCH * PROMPT_LEN * DIM * 4);
  float* w_h = (float*)carve((size_t)BATCH * PROMPT_LEN * DIM * 4);
  float* w_qkv = (float*)carve((size_t)BATCH * PROMPT_LEN * 3 * DIM * 4);
  float* w_att = (float*)carve((size_t)BATCH * PROMPT_LEN * DIM * 4);
  float* w_mlp = (float*)carve((size_t)BATCH * PROMPT_LEN * 4 * DIM * 4);
  float* w_kc = (float*)carve((size_t)NLAYER * BATCH * NHEAD * TMAX * HEADD * 4);
  float* w_vc = (float*)carve((size_t)NLAYER * BATCH * NHEAD * TMAX * HEADD * 4);
  float* w_xd0 = (float*)carve((size_t)DIM * BATCH * 4);
  float* w_xd1 = (float*)carve((size_t)DIM * BATCH * 4);
  float* w_ot = (float*)carve((size_t)DIM * BATCH * 4);
  float* w_qkp = (float*)carve((size_t)2 * BATCH * 3 * DIM * 4);
  float* w_aop = (float*)carve((size_t)2 * DIM * BATCH * 4);
  float* w_fcp = (float*)carve((size_t)2 * 4 * DIM * BATCH * 4);
  float* w_prp = (float*)carve((size_t)4 * DIM * BATCH * 4);
  float* w_logits = (float*)carve((size_t)BATCH * VOCAB * 4);
  unsigned* w_flags = (unsigned*)carve((size_t)GRIDN * FSTRIDE * 4);
  unsigned* w_go = (unsigned*)carve(256);

  const int M = BATCH * PROMPT_LEN;  // 1024
  const size_t kvstride = (size_t)BATCH * NHEAD * TMAX * HEADD;

  k_init<<<1, 256, 0, stream>>>(ids_in, mask_in, w_ids, w_lens, w_fin, w_csum, w_ccnt, w_flags,
                                w_go);
  k_embed_prefill<<<M, 256, 0, stream>>>(w_ids, wte, wpe, w_x);

  for (int l = 0; l < NLAYER; ++l) {
    float* kc = w_kc + (size_t)l * kvstride;
    float* vc = w_vc + (size_t)l * kvstride;
    k_layernorm<<<M, 256, 0, stream>>>(w_x, ln1_w + l * DIM, ln1_b + l * DIM, w_h);
    gemm_kernel<3><<<dim3(3 * DIM / 64, M / 64), 256, 0, stream>>>(
        w_h, qkv_w + (size_t)l * DIM * 3 * DIM, qkv_b + (size_t)l * 3 * DIM, nullptr, w_qkv, M,
        3 * DIM, DIM, kc, vc);
    k_attn_prefill<<<BATCH * NHEAD * PROMPT_LEN, 64, 0, stream>>>(w_qkv, kc, vc, w_att);
    gemm_kernel<2><<<dim3(DIM / 64, M / 64), 256, 0, stream>>>(
        w_att, ao_w + (size_t)l * DIM * DIM, ao_b + (size_t)l * DIM, w_x, w_x, M, DIM, DIM,
        nullptr, nullptr);
    k_layernorm<<<M, 256, 0, stream>>>(w_x, ln2_w + l * DIM, ln2_b + l * DIM, w_h);
    gemm_kernel<1><<<dim3(4 * DIM / 64, M / 64), 256, 0, stream>>>(
        w_h, fc_w + (size_t)l * DIM * 4 * DIM, fc_b + (size_t)l * 4 * DIM, nullptr, w_mlp, M,
        4 * DIM, DIM, nullptr, nullptr);
    gemm_kernel<2><<<dim3(DIM / 64, M / 64), 256, 0, stream>>>(
        w_mlp, pr_w + (size_t)l * 4 * DIM * DIM, pr_b + (size_t)l * DIM, w_x, w_x, M, DIM,
        4 * DIM, nullptr, nullptr);
  }

  // ---- persistent decode: one kernel, master-broadcast grid barriers ----
  DecArgs da;
  da.wte = wte;
  da.wpe = wpe;
  da.ln1_w = ln1_w;
  da.ln1_b = ln1_b;
  da.qkv_w = qkv_w;
  da.qkv_b = qkv_b;
  da.ao_w = ao_w;
  da.ao_b = ao_b;
  da.ln2_w = ln2_w;
  da.ln2_b = ln2_b;
  da.fc_w = fc_w;
  da.fc_b = fc_b;
  da.pr_w = pr_w;
  da.pr_b = pr_b;
  da.lnf_w = lnf_w;
  da.lnf_b = lnf_b;
  da.lm_w = lm_w;
  da.ids = w_ids;
  da.lens = w_lens;
  da.fin = w_fin;
  da.csum = w_csum;
  da.ccnt = w_ccnt;
  da.kc = w_kc;
  da.vc = w_vc;
  da.xd0 = w_xd0;
  da.xd1 = w_xd1;
  da.ot = w_ot;
  da.qkp = w_qkp;
  da.aop = w_aop;
  da.fcp = w_fcp;
  da.prp = w_prp;
  da.logits = w_logits;
  da.out = out;
  da.flags = w_flags;
  da.go = w_go;
  k_decode<<<GRIDN, 512, 0, stream>>>(da);
}

// Round 6
// 18243.951 us; speedup vs baseline: 1.5584x; 1.2442x over previous
//
#include <hip/hip_runtime.h>
#include <math.h>

#define VOCAB 8000
#define DIM 512
#define NLAYER 8
#define NHEAD 8
#define BATCH 16
#define TMAX 80
#define PROMPT_LEN 64
#define NNEW 16
#define HEADD 64
#define ATT_SCALE 0.125f

#define SRC_PLAIN 0
#define SRC_LN 1
#define SRC_GELU 2

// persistent decode kernel grid: 64 blocks x 512 thr, ~34KB LDS. Trivially
// co-resident on 256 CUs (1 block/4 CUs). Block 0 is the barrier master.
#define GRIDN 64
// flag stride in u32 units: 128B per flag line to avoid false sharing
#define FSTRIDE 32

__device__ __forceinline__ float gelu_f(float x) {
  return 0.5f * x * (1.0f + tanhf(0.7978845608028654f * (x + 0.044715f * x * x * x)));
}

// ---------- relaxed agent-scope atomic access helpers ----------
// These carry the coherence-scope bits (bypass L1/L2 to the device coherence
// point) WITHOUT emitting any cache-wide fence. All cross-block activation
// traffic uses these; weights and block-private data stay plain cached loads.
__device__ __forceinline__ float lda_f(const float* p) {
  return __hip_atomic_load(p, __ATOMIC_RELAXED, __HIP_MEMORY_SCOPE_AGENT);
}
__device__ __forceinline__ void sta_f(float* p, float v) {
  __hip_atomic_store(p, v, __ATOMIC_RELAXED, __HIP_MEMORY_SCOPE_AGENT);
}
__device__ __forceinline__ int lda_i(const int* p) {
  return __hip_atomic_load(p, __ATOMIC_RELAXED, __HIP_MEMORY_SCOPE_AGENT);
}
__device__ __forceinline__ void sta_i(int* p, int v) {
  __hip_atomic_store(p, v, __ATOMIC_RELAXED, __HIP_MEMORY_SCOPE_AGENT);
}
__device__ __forceinline__ unsigned lda_u(const unsigned* p) {
  return __hip_atomic_load(p, __ATOMIC_RELAXED, __HIP_MEMORY_SCOPE_AGENT);
}
__device__ __forceinline__ void sta_u(unsigned* p, unsigned v) {
  __hip_atomic_store(p, v, __ATOMIC_RELAXED, __HIP_MEMORY_SCOPE_AGENT);
}
__device__ __forceinline__ float4 lda4(const float4* p) {
  union {
    float4 f;
    unsigned long long d[2];
  } u;
  const unsigned long long* q = (const unsigned long long*)p;
  u.d[0] = __hip_atomic_load(q, __ATOMIC_RELAXED, __HIP_MEMORY_SCOPE_AGENT);
  u.d[1] = __hip_atomic_load(q + 1, __ATOMIC_RELAXED, __HIP_MEMORY_SCOPE_AGENT);
  return u.f;
}
__device__ __forceinline__ void sta4(float4* p, float4 v) {
  union {
    float4 f;
    unsigned long long d[2];
  } u;
  u.f = v;
  unsigned long long* q = (unsigned long long*)p;
  __hip_atomic_store(q, u.d[0], __ATOMIC_RELAXED, __HIP_MEMORY_SCOPE_AGENT);
  __hip_atomic_store(q + 1, u.d[1], __ATOMIC_RELAXED, __HIP_MEMORY_SCOPE_AGENT);
}

// ---------------- init ----------------
__global__ void k_init(const int* __restrict__ ids_in, const int* __restrict__ mask_in,
                       int* __restrict__ ids, int* __restrict__ lens, int* __restrict__ fin,
                       float* __restrict__ csum, float* __restrict__ ccnt,
                       unsigned* __restrict__ flags, unsigned* __restrict__ go) {
  int tid = threadIdx.x;
  for (int i = tid; i < BATCH * TMAX; i += blockDim.x) ids[i] = ids_in[i];
  // zero barrier state (graph replays reuse the workspace)
  for (int i = tid; i < GRIDN * FSTRIDE; i += blockDim.x) flags[i] = 0u;
  if (tid == 0) *go = 0u;
  if (tid < BATCH) {
    int s = 0;
    for (int t = 0; t < TMAX; ++t) s += mask_in[tid * TMAX + t];
    lens[tid] = s;
    fin[tid] = 0;
    csum[tid] = 0.f;
    ccnt[tid] = 0.f;
  }
}

// ---------------- prefill embedding ----------------
__global__ void k_embed_prefill(const int* __restrict__ ids, const float* __restrict__ wte,
                                const float* __restrict__ wpe, float* __restrict__ x) {
  int bt = blockIdx.x;
  int b = bt / PROMPT_LEN, t = bt % PROMPT_LEN;
  int tok = ids[b * TMAX + t];
  for (int d = threadIdx.x; d < DIM; d += blockDim.x)
    x[(size_t)bt * DIM + d] = wte[(size_t)tok * DIM + d] + wpe[(size_t)t * DIM + d];
}

// ---------------- prefill layernorm ----------------
__global__ void k_layernorm(const float* __restrict__ x, const float* __restrict__ w,
                            const float* __restrict__ b, float* __restrict__ out) {
  int row = blockIdx.x;
  int tid = threadIdx.x;
  const float* xr = x + (size_t)row * DIM;
  __shared__ float red[256];
  float v0 = xr[tid], v1 = xr[tid + 256];
  red[tid] = v0 + v1;
  __syncthreads();
  for (int s = 128; s > 0; s >>= 1) {
    if (tid < s) red[tid] += red[tid + s];
    __syncthreads();
  }
  float mean = red[0] * (1.0f / DIM);
  __syncthreads();
  float d0 = v0 - mean, d1 = v1 - mean;
  red[tid] = d0 * d0 + d1 * d1;
  __syncthreads();
  for (int s = 128; s > 0; s >>= 1) {
    if (tid < s) red[tid] += red[tid + s];
    __syncthreads();
  }
  float rstd = 1.0f / sqrtf(red[0] * (1.0f / DIM) + 1e-5f);
  out[(size_t)row * DIM + tid] = d0 * rstd * w[tid] + b[tid];
  out[(size_t)row * DIM + tid + 256] = d1 * rstd * w[tid + 256] + b[tid + 256];
}

// ---------------- prefill tiled GEMM ----------------
// MODE: 1 = gelu(+bias), 2 = +bias +res, 3 = qkv epilogue (+bias, write q + KV caches)
template <int MODE>
__global__ __launch_bounds__(256) void gemm_kernel(const float* __restrict__ A,
                                                   const float* __restrict__ W,
                                                   const float* __restrict__ bias,
                                                   const float* __restrict__ res,
                                                   float* __restrict__ C, int M, int N, int K,
                                                   float* __restrict__ kcT,
                                                   float* __restrict__ vc) {
  const int BM = 64, BN = 64, BK = 16;
  __shared__ float As[BK][BM + 4];
  __shared__ float Ws[BK][BN];
  int tid = threadIdx.x;
  int bm = blockIdx.y * BM, bn = blockIdx.x * BN;
  int tr = tid / 16, tc = tid % 16;
  float acc[4][4];
#pragma unroll
  for (int i = 0; i < 4; i++)
#pragma unroll
    for (int j = 0; j < 4; j++) acc[i][j] = 0.f;

  for (int k0 = 0; k0 < K; k0 += BK) {
    for (int i = tid; i < BM * BK; i += 256) {
      int m = i / BK, kk = i % BK;
      As[kk][m] = A[(size_t)(bm + m) * K + k0 + kk];
    }
    for (int i = tid; i < BK * BN; i += 256) {
      int kk = i / BN, n = i % BN;
      Ws[kk][n] = W[(size_t)(k0 + kk) * N + bn + n];
    }
    __syncthreads();
#pragma unroll
    for (int kk = 0; kk < BK; ++kk) {
      float a[4], w[4];
#pragma unroll
      for (int i = 0; i < 4; i++) a[i] = As[kk][tr * 4 + i];
#pragma unroll
      for (int j = 0; j < 4; j++) w[j] = Ws[kk][tc * 4 + j];
#pragma unroll
      for (int i = 0; i < 4; i++)
#pragma unroll
        for (int j = 0; j < 4; j++) acc[i][j] += a[i] * w[j];
    }
    __syncthreads();
  }
#pragma unroll
  for (int i = 0; i < 4; i++) {
    int m = bm + tr * 4 + i;
#pragma unroll
    for (int j = 0; j < 4; j++) {
      int n = bn + tc * 4 + j;
      float v = acc[i][j] + (bias ? bias[n] : 0.f);
      if (MODE == 1) v = gelu_f(v);
      if (MODE == 2) v += res[(size_t)m * N + n];
      if (MODE == 3) {
        int b = m >> 6, t = m & 63;
        if (n < DIM) {
          C[(size_t)m * N + n] = v;  // q (only q region consumed)
        } else if (n < 2 * DIM) {
          int dd = n - DIM;
          kcT[((size_t)(b * NHEAD + (dd >> 6)) * HEADD + (dd & 63)) * TMAX + t] = v;
        } else {
          int dd = n - 2 * DIM;
          vc[((size_t)(b * NHEAD + (dd >> 6)) * TMAX + t) * HEADD + (dd & 63)] = v;
        }
      } else {
        C[(size_t)m * N + n] = v;
      }
    }
  }
}

// ---------------- prefill attention (K^T cache layout) ----------------
__global__ void k_attn_prefill(const float* __restrict__ qkv, const float* __restrict__ kcT,
                               const float* __restrict__ vc, float* __restrict__ o) {
  int blk = blockIdx.x;
  int q = blk % PROMPT_LEN;
  int bh = blk / PROMPT_LEN;
  int h = bh % NHEAD, b = bh / NHEAD;
  int tid = threadIdx.x;  // 64
  __shared__ float qs[HEADD];
  __shared__ float ps[PROMPT_LEN];
  qs[tid] = qkv[(size_t)(b * PROMPT_LEN + q) * 3 * DIM + h * HEADD + tid];
  __syncthreads();
  const float* kbT = kcT + (size_t)(b * NHEAD + h) * HEADD * TMAX;  // [64][80]
  const float* vb = vc + (size_t)(b * NHEAD + h) * TMAX * HEADD;    // [80][64]
  float s = -1e30f;
  if (tid <= q) {
    float a = 0.f;
    for (int d = 0; d < HEADD; ++d) a += qs[d] * kbT[d * TMAX + tid];
    s = a * ATT_SCALE;
  }
  float mx = s;
  for (int off = 32; off > 0; off >>= 1) mx = fmaxf(mx, __shfl_xor(mx, off));
  float e = (tid <= q) ? expf(s - mx) : 0.f;
  float sum = e;
  for (int off = 32; off > 0; off >>= 1) sum += __shfl_xor(sum, off);
  ps[tid] = e / sum;
  __syncthreads();
  float acc = 0.f;
  for (int t = 0; t <= q; ++t) acc += ps[t] * vb[t * HEADD + tid];
  o[(size_t)(b * PROMPT_LEN + q) * DIM + h * HEADD + tid] = acc;
}

// ================= persistent decode kernel =================

struct SmGemm {
  float sm[DIM * BATCH];  // 8192 floats, max SROWS*BATCH over all stages
  float wsum[8][BATCH];
  float wss[8][BATCH];
  float smean[BATCH], srstd[BATCH];
};
struct SmAttn {
  float qs[8][HEADD];
  float ps[8][TMAX];
};
struct SmUpd {
  float vred[512];
  int ired[512];
  int sh_tok, sh_pos;
};
union SmAll {
  SmGemm g;
  SmAttn a;
  SmUpd u;
};

// Grid barrier, master-broadcast form, FENCE-FREE:
//  - all cross-block data moves via relaxed agent-scope atomics (coherent at
//    the device coherence point; no stale L1/L2 involved), so the barrier
//    needs NO __threadfence (which lowers to L2-wide writeback/invalidate and
//    was the measured ~25us/phase cost + per-step weight re-fetch in r1/r2/r5).
//  - ordering: each wave drains vmcnt(0) at the __syncthreads before arrival
//    (compiler-enforced), so the flag store is ordered after all data stores.
__device__ __forceinline__ void gsync(unsigned* __restrict__ flags, unsigned* __restrict__ go,
                                      unsigned gen) {
  __syncthreads();
  if (threadIdx.x == 0) sta_u(&flags[(unsigned)blockIdx.x * FSTRIDE], gen);
  if (blockIdx.x == 0) {
    if (threadIdx.x < GRIDN) {  // one wave: lanes 0..63 poll flags 0..63
      while (lda_u(&flags[threadIdx.x * FSTRIDE]) < gen) __builtin_amdgcn_s_sleep(1);
    }
    // wave reconverged: all arrivals observed
    if (threadIdx.x == 0) sta_u(go, gen);
  }
  if (threadIdx.x == 0) {
    while (lda_u(go) < gen) __builtin_amdgcn_s_sleep(1);
  }
  __syncthreads();
}

// ---------------- decode skinny GEMM stage (device fn; 512 threads) ----------------
// C[16,N] = A^T[16,K] @ W[K,N]. A ([K][16]) is built in LDS from:
//   SRC_PLAIN: src            SRC_LN: ln(src + sum parts) (full-K stage; opt. write xd)
//   SRC_GELU: gelu(sum parts)
// 8 waves = 2 batch-groups x 4 k-chunks. KB = cross-block split-K (partials out,
// bias folded into partial kb==0). LAYOUT: 0 row-major [kb][16][N], 1 transposed [kb][N][16].
// Cross-block activations (src/parts/out/xdout) via relaxed agent atomics;
// weights (W/lnw/lnb/bias) via plain cached loads (read-only, L2-resident).
template <int KB, int SRC, int P, int LAYOUT, bool BIAS, bool XDW, int N, int K>
__device__ __forceinline__ void skinny_stage(SmGemm& S, int bx, int by,
                                             const float* __restrict__ src,
                                             const float* __restrict__ parts,
                                             const float* __restrict__ lnw,
                                             const float* __restrict__ lnb,
                                             const float* __restrict__ bias,
                                             const float* __restrict__ W, float* __restrict__ out,
                                             float* __restrict__ xdout) {
  constexpr int KRANGE = K / KB;
  constexpr int SROWS = (SRC == SRC_LN) ? K : KRANGE;
  float* sm = S.sm;
  const int tid = threadIdx.x;
  const int base_row = (SRC == SRC_LN) ? 0 : by * KRANGE;

  // ---- stage ----
  {
    const float4* s4 = (const float4*)src;
    float4* d4 = (float4*)sm;
    constexpr int NF4 = SROWS * BATCH / 4;
    for (int i = tid; i < NF4; i += 512) {
      int gi = base_row * (BATCH / 4) + i;
      float4 v;
      if (SRC == SRC_GELU) {
        v = make_float4(0.f, 0.f, 0.f, 0.f);
      } else {
        v = lda4(s4 + gi);
      }
#pragma unroll
      for (int p = 0; p < P; ++p) {
        const float4* p4 = (const float4*)(parts + (size_t)p * K * BATCH);
        float4 t = lda4(p4 + gi);
        v.x += t.x;
        v.y += t.y;
        v.z += t.z;
        v.w += t.w;
      }
      if (SRC == SRC_GELU) {
        v.x = gelu_f(v.x);
        v.y = gelu_f(v.y);
        v.z = gelu_f(v.z);
        v.w = gelu_f(v.w);
      }
      if (XDW) {
        if (bx == 0 && by == 0) sta4(((float4*)xdout) + gi, v);
      }
      d4[i] = v;
    }
  }
  if (SRC == SRC_LN) {
    __syncthreads();
    float s = 0.f, ss = 0.f;
#pragma unroll
    for (int j = 0; j < 16; ++j) {
      float v = sm[tid + 512 * j];
      s += v;
      ss += v * v;
    }
    s += __shfl_xor(s, 16);
    ss += __shfl_xor(ss, 16);
    s += __shfl_xor(s, 32);
    ss += __shfl_xor(ss, 32);
    int lane0 = tid & 63, w0 = tid >> 6;
    if (lane0 < BATCH) {
      S.wsum[w0][lane0] = s;
      S.wss[w0][lane0] = ss;
    }
    __syncthreads();
    if (tid < BATCH) {
      float ts = 0.f, tss = 0.f;
#pragma unroll
      for (int ww = 0; ww < 8; ++ww) {
        ts += S.wsum[ww][tid];
        tss += S.wss[ww][tid];
      }
      float m = ts * (1.0f / K);
      float var = tss * (1.0f / K) - m * m;
      S.smean[tid] = m;
      S.srstd[tid] = 1.0f / sqrtf(var + 1e-5f);
    }
    __syncthreads();
    float mb = S.smean[tid & 15];
    float rb = S.srstd[tid & 15];
#pragma unroll
    for (int j = 0; j < 16; ++j) {
      int idx = tid + 512 * j;
      int k = idx >> 4;
      sm[idx] = (sm[idx] - mb) * rb * lnw[k] + lnb[k];
    }
  }
  __syncthreads();

  // ---- K-loop ----
  const int lane = tid & 63;
  const int w = tid >> 6;
  const int bw = w & 1;
  const int kw = w >> 1;
  constexpr int KCH = KRANGE / 4;
  const int col = bx * 64 + lane;
  const float* Wp = W + (size_t)(by * KRANGE + kw * KCH) * N + col;
  const int fbase = ((SRC == SRC_LN) ? by * KRANGE : 0) + kw * KCH;
  float acc[8];
#pragma unroll
  for (int i = 0; i < 8; ++i) acc[i] = 0.f;
  for (int k = 0; k < KCH; k += 8) {
    float wv[8];
#pragma unroll
    for (int u = 0; u < 8; ++u) wv[u] = Wp[(size_t)(k + u) * N];
#pragma unroll
    for (int u = 0; u < 8; ++u) {
      const float4* a4 = (const float4*)&sm[(fbase + k + u) * BATCH + bw * 8];
      float4 A0 = a4[0], A1 = a4[1];
      acc[0] = fmaf(A0.x, wv[u], acc[0]);
      acc[1] = fmaf(A0.y, wv[u], acc[1]);
      acc[2] = fmaf(A0.z, wv[u], acc[2]);
      acc[3] = fmaf(A0.w, wv[u], acc[3]);
      acc[4] = fmaf(A1.x, wv[u], acc[4]);
      acc[5] = fmaf(A1.y, wv[u], acc[5]);
      acc[6] = fmaf(A1.z, wv[u], acc[6]);
      acc[7] = fmaf(A1.w, wv[u], acc[7]);
    }
  }
  __syncthreads();
#pragma unroll
  for (int i = 0; i < 8; ++i) sm[(w * 8 + i) * 64 + lane] = acc[i];
  __syncthreads();
  for (int o = tid; o < BATCH * 64; o += 512) {
    int b, gn_l;
    if (LAYOUT == 1) {
      b = o & 15;
      gn_l = o >> 4;
    } else {
      b = o >> 6;
      gn_l = o & 63;
    }
    int bw2 = b >> 3, bi = b & 7;
    float v = 0.f;
#pragma unroll
    for (int k2 = 0; k2 < 4; ++k2) v += sm[(((k2 * 2 + bw2) * 8) + bi) * 64 + gn_l];
    int gn = bx * 64 + gn_l;
    if (BIAS && by == 0) v += bias[gn];
    if (KB == 1 && LAYOUT == 0)
      sta_f(&out[(size_t)b * N + gn], v);
    else if (LAYOUT == 0)
      sta_f(&out[((size_t)by * BATCH + b) * N + gn], v);
    else
      sta_f(&out[(size_t)by * N * BATCH + (size_t)gn * BATCH + b], v);
  }
  // a block may run another virtual tile immediately after this one (e.g. the
  // 125-tile logits stage on 64 blocks): ensure all waves finished reading sm
  // before the next tile's staging overwrites it.
  __syncthreads();
}

// ---------------- decode attention stage (8 waves/block, wave = one (b,h)) ----------------
// KV cache slices for (b,h) are appended and read by the SAME block every step
// (stable vb = blk mapping, blk persists on one CU) -> plain cached KV is safe.
__device__ __forceinline__ void attn_stage(SmAttn& S, int blk, const float* __restrict__ qp,
                                           const int* __restrict__ lens, float* __restrict__ kcT,
                                           float* __restrict__ vc, float* __restrict__ ot) {
  const int tid = threadIdx.x;
  const int d = tid & 63;
  const int wv = tid >> 6;
  const int bh = blk * 8 + wv;  // = b*NHEAD + h
  const int h = bh % NHEAD, b = bh / NHEAD;
  int p = lda_i(&lens[b]) - 1;
  if (p < 0) p = 0;
  if (p > TMAX - 1) p = TMAX - 1;
  const float* q0 = qp + (size_t)b * 3 * DIM + h * HEADD;
  const float* q1 = qp + (size_t)BATCH * 3 * DIM + (size_t)b * 3 * DIM + h * HEADD;
  float qv = lda_f(q0 + d) + lda_f(q1 + d);
  float kself = lda_f(q0 + DIM + d) + lda_f(q1 + DIM + d);
  float vself = lda_f(q0 + 2 * DIM + d) + lda_f(q1 + 2 * DIM + d);
  float* kT = kcT + (size_t)bh * HEADD * TMAX;  // [64][80]
  float* vb = vc + (size_t)bh * TMAX * HEADD;   // [80][64]
  kT[d * TMAX + p] = kself;
  vb[p * HEADD + d] = vself;
  float* qs = S.qs[wv];
  float* ps = S.ps[wv];
  qs[d] = qv;
  __syncthreads();
  float pd = qv * kself;
  for (int off = 32; off > 0; off >>= 1) pd += __shfl_xor(pd, off);
  float selfdot = pd * ATT_SCALE;
  float s0 = -1e30f, s1 = -1e30f;
  int t1 = d + 64;
  if (d < p) {
    float a = 0.f;
    for (int dd = 0; dd < HEADD; ++dd) a += qs[dd] * kT[dd * TMAX + d];
    s0 = a * ATT_SCALE;
  } else if (d == p) {
    s0 = selfdot;
  }
  if (t1 < p) {
    float a = 0.f;
    for (int dd = 0; dd < HEADD; ++dd) a += qs[dd] * kT[dd * TMAX + t1];
    s1 = a * ATT_SCALE;
  } else if (t1 == p) {
    s1 = selfdot;
  }
  float mx = fmaxf(s0, s1);
  for (int off = 32; off > 0; off >>= 1) mx = fmaxf(mx, __shfl_xor(mx, off));
  float e0 = (d <= p) ? expf(s0 - mx) : 0.f;
  float e1 = (t1 <= p) ? expf(s1 - mx) : 0.f;
  float sum = e0 + e1;
  for (int off = 32; off > 0; off >>= 1) sum += __shfl_xor(sum, off);
  float inv = 1.f / sum;
  ps[d] = e0 * inv;
  if (d < TMAX - 64) ps[t1] = e1 * inv;
  __syncthreads();
  float acc = 0.f;
  for (int t = 0; t < p; ++t) acc += ps[t] * vb[t * HEADD + d];
  acc += ps[p] * vself;
  sta_f(&ot[(size_t)(h * HEADD + d) * BATCH + b], acc);
  __syncthreads();
}

// ---------------- decode update stage (512 threads, one batch element) ----------------
__device__ __forceinline__ void update_stage(SmUpd& S, int b, const float* __restrict__ logits,
                                             int* ids, int* lens, int* fin, float* csum,
                                             float* ccnt, float* out_gen, int step,
                                             const float* __restrict__ wte,
                                             const float* __restrict__ wpe, float* xdT) {
  const int tid = threadIdx.x;
  const float* lr = logits + (size_t)b * VOCAB;
  float best = -1e30f;
  int besti = 0;
  for (int i = tid; i < VOCAB; i += 512) {
    float v = lda_f(&lr[i]);
    if (v > best) {
      best = v;
      besti = i;
    }
  }
  S.vred[tid] = best;
  S.ired[tid] = besti;
  __syncthreads();
  for (int s = 256; s > 0; s >>= 1) {
    if (tid < s) {
      if (S.vred[tid + s] > S.vred[tid] ||
          (S.vred[tid + s] == S.vred[tid] && S.ired[tid + s] < S.ired[tid])) {
        S.vred[tid] = S.vred[tid + s];
        S.ired[tid] = S.ired[tid + s];
      }
    }
    __syncthreads();
  }
  float mx = S.vred[0];
  int top = S.ired[0];
  __syncthreads();
  float se = 0.f;
  for (int i = tid; i < VOCAB; i += 512) se += expf(lda_f(&lr[i]) - mx);
  S.vred[tid] = se;
  __syncthreads();
  for (int s = 256; s > 0; s >>= 1) {
    if (tid < s) S.vred[tid] += S.vred[tid + s];
    __syncthreads();
  }
  if (tid == 0) {
    float top_p = 1.f / S.vred[0];
    int l = lda_i(&lens[b]);
    int fb = lda_i(&fin[b]);
    bool active = (!fb) && (l < TMAX);
    if (active) {
      sta_f(&csum[b], lda_f(&csum[b]) + top_p);
      sta_f(&ccnt[b], lda_f(&ccnt[b]) + 1.f);
    }
    bool is_end = (top == 3) || (top == 0);
    bool wr = active && !is_end;
    if (wr) {
      sta_i(&ids[b * TMAX + l], top);
      sta_i(&lens[b], l + 1);
    }
    if (active && is_end) sta_i(&fin[b], 1);
    out_gen[b * NNEW + step] = wr ? (float)top : 0.f;
    int l2 = wr ? l + 1 : l;
    int pn = l2 - 1;
    if (pn < 0) pn = 0;
    if (pn > TMAX - 1) pn = TMAX - 1;
    S.sh_pos = pn;
    // when wr, slot pn==l holds `top` (just stored by this thread) — use the
    // register value to avoid a same-address store->load in-flight hazard.
    S.sh_tok = wr ? top : lda_i(&ids[b * TMAX + pn]);
  }
  __syncthreads();
  int tok = S.sh_tok, pn = S.sh_pos;
  sta_f(&xdT[(size_t)tid * BATCH + b],
        wte[(size_t)tok * DIM + tid] + wpe[(size_t)pn * DIM + tid]);
  __syncthreads();
}

struct DecArgs {
  const float *wte, *wpe, *ln1_w, *ln1_b, *qkv_w, *qkv_b, *ao_w, *ao_b, *ln2_w, *ln2_b;
  const float *fc_w, *fc_b, *pr_w, *pr_b, *lnf_w, *lnf_b, *lm_w;
  int *ids, *lens, *fin;
  float *csum, *ccnt;
  float *kc, *vc;
  float *xd0, *xd1, *ot, *qkp, *aop, *fcp, *prp, *logits;
  float* out;
  unsigned *flags, *go;
};

__global__ __launch_bounds__(512) void k_decode(DecArgs a) {
  __shared__ SmAll sm;
  const int blk = blockIdx.x;
  const int tid = threadIdx.x;
  const size_t kvstride = (size_t)BATCH * NHEAD * TMAX * HEADD;
  unsigned gen = 0;

  // embed0: xd0[d][b] = wte[tok] + wpe[pos]   (lens/ids from k_init: kernel
  // boundary already made them visible; xd0 is cross-block -> atomic store)
  if (blk < BATCH) {
    int b = blk;
    int p = a.lens[b] - 1;
    if (p < 0) p = 0;
    if (p > TMAX - 1) p = TMAX - 1;
    int tok = a.ids[b * TMAX + p];
    sta_f(&a.xd0[(size_t)tid * BATCH + b],
          a.wte[(size_t)tok * DIM + tid] + a.wpe[(size_t)p * DIM + tid]);
  }
  gsync(a.flags, a.go, ++gen);

  for (int s = 0; s < NNEW; ++s) {
    for (int l = 0; l < NLAYER; ++l) {
      float* kc = a.kc + (size_t)l * kvstride;
      float* vc = a.vc + (size_t)l * kvstride;
      // QKV: ln1(xd) @ qkv_w -> 2 row-major partials [2][16][1536]  (48 tiles)
      for (int vb = blk; vb < 48; vb += GRIDN) {
        if (l == 0)
          skinny_stage<2, SRC_LN, 0, 0, true, false, 3 * DIM, DIM>(
              sm.g, vb % 24, vb / 24, a.xd0, nullptr, a.ln1_w + l * DIM, a.ln1_b + l * DIM,
              a.qkv_b + (size_t)l * 3 * DIM, a.qkv_w + (size_t)l * DIM * 3 * DIM, a.qkp, nullptr);
        else
          skinny_stage<2, SRC_LN, 4, 0, true, true, 3 * DIM, DIM>(
              sm.g, vb % 24, vb / 24, a.xd1, a.prp, a.ln1_w + l * DIM, a.ln1_b + l * DIM,
              a.qkv_b + (size_t)l * 3 * DIM, a.qkv_w + (size_t)l * DIM * 3 * DIM, a.qkp, a.xd0);
      }
      gsync(a.flags, a.go, ++gen);
      // attention: sums 2 qkv partials, appends KV, Ot[512][16]  (16 tiles)
      for (int vb = blk; vb < 16; vb += GRIDN)
        attn_stage(sm.a, vb, a.qkp, a.lens, kc, vc, a.ot);
      gsync(a.flags, a.go, ++gen);
      // AO: Ot @ ao_w -> 2 transposed partials [2][512][16]  (16 tiles)
      for (int vb = blk; vb < 16; vb += GRIDN)
        skinny_stage<2, SRC_PLAIN, 0, 1, true, false, DIM, DIM>(
            sm.g, vb % 8, vb / 8, a.ot, nullptr, nullptr, nullptr, a.ao_b + (size_t)l * DIM,
            a.ao_w + (size_t)l * DIM * DIM, a.aop, nullptr);
      gsync(a.flags, a.go, ++gen);
      // FC: ln2(xd0 + 2 ao partials) @ fc_w -> 2 transposed partials; write xd1  (64 tiles)
      for (int vb = blk; vb < 64; vb += GRIDN)
        skinny_stage<2, SRC_LN, 2, 1, true, true, 4 * DIM, DIM>(
            sm.g, vb % 32, vb / 32, a.xd0, a.aop, a.ln2_w + l * DIM, a.ln2_b + l * DIM,
            a.fc_b + (size_t)l * 4 * DIM, a.fc_w + (size_t)l * DIM * 4 * DIM, a.fcp, a.xd1);
      gsync(a.flags, a.go, ++gen);
      // PR: gelu(sum 2 fc partials) @ pr_w -> 4 transposed partials [4][512][16]  (32 tiles)
      for (int vb = blk; vb < 32; vb += GRIDN)
        skinny_stage<4, SRC_GELU, 2, 1, true, false, DIM, 4 * DIM>(
            sm.g, vb % 8, vb / 8, nullptr, a.fcp, nullptr, nullptr, a.pr_b + (size_t)l * DIM,
            a.pr_w + (size_t)l * 4 * DIM * DIM, a.prp, nullptr);
      gsync(a.flags, a.go, ++gen);
    }
    // logits = lnf(xd1 + 4 pr partials)^T @ lm_w  (lnf fused; 125 tiles -> 2 rounds)
    for (int vb = blk; vb < VOCAB / 64; vb += GRIDN)
      skinny_stage<1, SRC_LN, 4, 0, false, false, VOCAB, DIM>(
          sm.g, vb, 0, a.xd1, a.prp, a.lnf_w, a.lnf_b, nullptr, a.lm_w, a.logits, nullptr);
    gsync(a.flags, a.go, ++gen);
    // update state + embed next token -> xd0  (16 tiles)
    for (int vb = blk; vb < BATCH; vb += GRIDN)
      update_stage(sm.u, vb, a.logits, a.ids, a.lens, a.fin, a.csum, a.ccnt, a.out, s, a.wte,
                   a.wpe, a.xd0);
    gsync(a.flags, a.go, ++gen);
  }
  // finalize confidences (cross-block reads of csum/ccnt -> atomic loads)
  if (blk == 0 && tid < BATCH)
    a.out[BATCH * NNEW + tid] = lda_f(&a.csum[tid]) / fmaxf(lda_f(&a.ccnt[tid]), 1.f);
}

// ---------------- host launch ----------------
extern "C" void kernel_launch(void* const* d_in, const int* in_sizes, int n_in, void* d_out,
                              int out_size, void* d_ws, size_t ws_size, hipStream_t stream) {
  const float* wte = (const float*)d_in[0];
  const float* wpe = (const float*)d_in[1];
  const float* ln1_w = (const float*)d_in[2];
  const float* ln1_b = (const float*)d_in[3];
  const float* qkv_w = (const float*)d_in[4];
  const float* qkv_b = (const float*)d_in[5];
  const float* ao_w = (const float*)d_in[6];
  const float* ao_b = (const float*)d_in[7];
  const float* ln2_w = (const float*)d_in[8];
  const float* ln2_b = (const float*)d_in[9];
  const float* fc_w = (const float*)d_in[10];
  const float* fc_b = (const float*)d_in[11];
  const float* pr_w = (const float*)d_in[12];
  const float* pr_b = (const float*)d_in[13];
  const float* lnf_w = (const float*)d_in[14];
  const float* lnf_b = (const float*)d_in[15];
  const float* lm_w = (const float*)d_in[16];
  const int* ids_in = (const int*)d_in[17];
  const int* mask_in = (const int*)d_in[18];
  float* out = (float*)d_out;

  char* p = (char*)d_ws;
  auto carve = [&](size_t nbytes) {
    char* r = p;
    p += (nbytes + 255) & ~(size_t)255;
    return (void*)r;
  };
  int* w_ids = (int*)carve(BATCH * TMAX * 4);
  int* w_lens = (int*)carve(BATCH * 4);
  int* w_fin = (int*)carve(BATCH * 4);
  float* w_csum = (float*)carve(BATCH * 4);
  float* w_ccnt = (float*)carve(BATCH * 4);
  float* w_x = (float*)carve((size_t)BATCH * PROMPT_LEN * DIM * 4);
  float* w_h = (float*)carve((size_t)BATCH * PROMPT_LEN * DIM * 4);
  float* w_qkv = (float*)carve((size_t)BATCH * PROMPT_LEN * 3 * DIM * 4);
  float* w_att = (float*)carve((size_t)BATCH * PROMPT_LEN * DIM * 4);
  float* w_mlp = (float*)carve((size_t)BATCH * PROMPT_LEN * 4 * DIM * 4);
  float* w_kc = (float*)carve((size_t)NLAYER * BATCH * NHEAD * TMAX * HEADD * 4);
  float* w_vc = (float*)carve((size_t)NLAYER * BATCH * NHEAD * TMAX * HEADD * 4);
  float* w_xd0 = (float*)carve((size_t)DIM * BATCH * 4);
  float* w_xd1 = (float*)carve((size_t)DIM * BATCH * 4);
  float* w_ot = (float*)carve((size_t)DIM * BATCH * 4);
  float* w_qkp = (float*)carve((size_t)2 * BATCH * 3 * DIM * 4);
  float* w_aop = (float*)carve((size_t)2 * DIM * BATCH * 4);
  float* w_fcp = (float*)carve((size_t)2 * 4 * DIM * BATCH * 4);
  float* w_prp = (float*)carve((size_t)4 * DIM * BATCH * 4);
  float* w_logits = (float*)carve((size_t)BATCH * VOCAB * 4);
  unsigned* w_flags = (unsigned*)carve((size_t)GRIDN * FSTRIDE * 4);
  unsigned* w_go = (unsigned*)carve(256);

  const int M = BATCH * PROMPT_LEN;  // 1024
  const size_t kvstride = (size_t)BATCH * NHEAD * TMAX * HEADD;

  k_init<<<1, 256, 0, stream>>>(ids_in, mask_in, w_ids, w_lens, w_fin, w_csum, w_ccnt, w_flags,
                                w_go);
  k_embed_prefill<<<M, 256, 0, stream>>>(w_ids, wte, wpe, w_x);

  for (int l = 0; l < NLAYER; ++l) {
    float* kc = w_kc + (size_t)l * kvstride;
    float* vc = w_vc + (size_t)l * kvstride;
    k_layernorm<<<M, 256, 0, stream>>>(w_x, ln1_w + l * DIM, ln1_b + l * DIM, w_h);
    gemm_kernel<3><<<dim3(3 * DIM / 64, M / 64), 256, 0, stream>>>(
        w_h, qkv_w + (size_t)l * DIM * 3 * DIM, qkv_b + (size_t)l * 3 * DIM, nullptr, w_qkv, M,
        3 * DIM, DIM, kc, vc);
    k_attn_prefill<<<BATCH * NHEAD * PROMPT_LEN, 64, 0, stream>>>(w_qkv, kc, vc, w_att);
    gemm_kernel<2><<<dim3(DIM / 64, M / 64), 256, 0, stream>>>(
        w_att, ao_w + (size_t)l * DIM * DIM, ao_b + (size_t)l * DIM, w_x, w_x, M, DIM, DIM,
        nullptr, nullptr);
    k_layernorm<<<M, 256, 0, stream>>>(w_x, ln2_w + l * DIM, ln2_b + l * DIM, w_h);
    gemm_kernel<1><<<dim3(4 * DIM / 64, M / 64), 256, 0, stream>>>(
        w_h, fc_w + (size_t)l * DIM * 4 * DIM, fc_b + (size_t)l * 4 * DIM, nullptr, w_mlp, M,
        4 * DIM, DIM, nullptr, nullptr);
    gemm_kernel<2><<<dim3(DIM / 64, M / 64), 256, 0, stream>>>(
        w_mlp, pr_w + (size_t)l * 4 * DIM * DIM, pr_b + (size_t)l * DIM, w_x, w_x, M, DIM,
        4 * DIM, nullptr, nullptr);
  }

  // ---- persistent decode: one kernel, fence-free scoped-atomic barriers ----
  DecArgs da;
  da.wte = wte;
  da.wpe = wpe;
  da.ln1_w = ln1_w;
  da.ln1_b = ln1_b;
  da.qkv_w = qkv_w;
  da.qkv_b = qkv_b;
  da.ao_w = ao_w;
  da.ao_b = ao_b;
  da.ln2_w = ln2_w;
  da.ln2_b = ln2_b;
  da.fc_w = fc_w;
  da.fc_b = fc_b;
  da.pr_w = pr_w;
  da.pr_b = pr_b;
  da.lnf_w = lnf_w;
  da.lnf_b = lnf_b;
  da.lm_w = lm_w;
  da.ids = w_ids;
  da.lens = w_lens;
  da.fin = w_fin;
  da.csum = w_csum;
  da.ccnt = w_ccnt;
  da.kc = w_kc;
  da.vc = w_vc;
  da.xd0 = w_xd0;
  da.xd1 = w_xd1;
  da.ot = w_ot;
  da.qkp = w_qkp;
  da.aop = w_aop;
  da.fcp = w_fcp;
  da.prp = w_prp;
  da.logits = w_logits;
  da.out = out;
  da.flags = w_flags;
  da.go = w_go;
  k_decode<<<GRIDN, 512, 0, stream>>>(da);
}

// Round 7
// 17202.068 us; speedup vs baseline: 1.6528x; 1.0606x over previous
//
#include <hip/hip_runtime.h>
#include <math.h>

#define VOCAB 8000
#define DIM 512
#define NLAYER 8
#define NHEAD 8
#define BATCH 16
#define TMAX 80
#define PROMPT_LEN 64
#define NNEW 16
#define HEADD 64
#define ATT_SCALE 0.125f

#define SRC_PLAIN 0
#define SRC_LN 1
#define SRC_GELU 2

// persistent decode kernel grid: 256 blocks x 512 thr (1 block/CU), ~34KB LDS.
// Capacity is 2 blocks/CU at 128 VGPR, so 256 blocks are co-resident no matter
// how the scheduler places them. Block 0 is the barrier master.
#define GRIDN 256
// flag stride in u32 units: 128B per flag line to avoid false sharing
#define FSTRIDE 32

__device__ __forceinline__ float gelu_f(float x) {
  return 0.5f * x * (1.0f + tanhf(0.7978845608028654f * (x + 0.044715f * x * x * x)));
}

// ---------- relaxed agent-scope atomic access helpers ----------
// Scope bits give cross-XCD visibility at the device coherence point without
// any cache-wide fence (the fences were the measured ~25us/phase in r1/r2/r5).
__device__ __forceinline__ float lda_f(const float* p) {
  return __hip_atomic_load(p, __ATOMIC_RELAXED, __HIP_MEMORY_SCOPE_AGENT);
}
__device__ __forceinline__ void sta_f(float* p, float v) {
  __hip_atomic_store(p, v, __ATOMIC_RELAXED, __HIP_MEMORY_SCOPE_AGENT);
}
__device__ __forceinline__ int lda_i(const int* p) {
  return __hip_atomic_load(p, __ATOMIC_RELAXED, __HIP_MEMORY_SCOPE_AGENT);
}
__device__ __forceinline__ void sta_i(int* p, int v) {
  __hip_atomic_store(p, v, __ATOMIC_RELAXED, __HIP_MEMORY_SCOPE_AGENT);
}
__device__ __forceinline__ unsigned lda_u(const unsigned* p) {
  return __hip_atomic_load(p, __ATOMIC_RELAXED, __HIP_MEMORY_SCOPE_AGENT);
}
__device__ __forceinline__ void sta_u(unsigned* p, unsigned v) {
  __hip_atomic_store(p, v, __ATOMIC_RELAXED, __HIP_MEMORY_SCOPE_AGENT);
}
__device__ __forceinline__ float4 lda4(const float4* p) {
  union {
    float4 f;
    unsigned long long d[2];
  } u;
  const unsigned long long* q = (const unsigned long long*)p;
  u.d[0] = __hip_atomic_load(q, __ATOMIC_RELAXED, __HIP_MEMORY_SCOPE_AGENT);
  u.d[1] = __hip_atomic_load(q + 1, __ATOMIC_RELAXED, __HIP_MEMORY_SCOPE_AGENT);
  return u.f;
}
__device__ __forceinline__ void sta4(float4* p, float4 v) {
  union {
    float4 f;
    unsigned long long d[2];
  } u;
  u.f = v;
  unsigned long long* q = (unsigned long long*)p;
  __hip_atomic_store(q, u.d[0], __ATOMIC_RELAXED, __HIP_MEMORY_SCOPE_AGENT);
  __hip_atomic_store(q + 1, u.d[1], __ATOMIC_RELAXED, __HIP_MEMORY_SCOPE_AGENT);
}

// ---------------- init ----------------
__global__ void k_init(const int* __restrict__ ids_in, const int* __restrict__ mask_in,
                       int* __restrict__ ids, int* __restrict__ lens, int* __restrict__ fin,
                       float* __restrict__ csum, float* __restrict__ ccnt,
                       unsigned* __restrict__ flags, unsigned* __restrict__ go) {
  int tid = threadIdx.x;
  for (int i = tid; i < BATCH * TMAX; i += blockDim.x) ids[i] = ids_in[i];
  // zero barrier state (graph replays reuse the workspace)
  for (int i = tid; i < GRIDN * FSTRIDE; i += blockDim.x) flags[i] = 0u;
  if (tid == 0) *go = 0u;
  if (tid < BATCH) {
    int s = 0;
    for (int t = 0; t < TMAX; ++t) s += mask_in[tid * TMAX + t];
    lens[tid] = s;
    fin[tid] = 0;
    csum[tid] = 0.f;
    ccnt[tid] = 0.f;
  }
}

// ---------------- prefill embedding ----------------
__global__ void k_embed_prefill(const int* __restrict__ ids, const float* __restrict__ wte,
                                const float* __restrict__ wpe, float* __restrict__ x) {
  int bt = blockIdx.x;
  int b = bt / PROMPT_LEN, t = bt % PROMPT_LEN;
  int tok = ids[b * TMAX + t];
  for (int d = threadIdx.x; d < DIM; d += blockDim.x)
    x[(size_t)bt * DIM + d] = wte[(size_t)tok * DIM + d] + wpe[(size_t)t * DIM + d];
}

// ---------------- prefill layernorm ----------------
__global__ void k_layernorm(const float* __restrict__ x, const float* __restrict__ w,
                            const float* __restrict__ b, float* __restrict__ out) {
  int row = blockIdx.x;
  int tid = threadIdx.x;
  const float* xr = x + (size_t)row * DIM;
  __shared__ float red[256];
  float v0 = xr[tid], v1 = xr[tid + 256];
  red[tid] = v0 + v1;
  __syncthreads();
  for (int s = 128; s > 0; s >>= 1) {
    if (tid < s) red[tid] += red[tid + s];
    __syncthreads();
  }
  float mean = red[0] * (1.0f / DIM);
  __syncthreads();
  float d0 = v0 - mean, d1 = v1 - mean;
  red[tid] = d0 * d0 + d1 * d1;
  __syncthreads();
  for (int s = 128; s > 0; s >>= 1) {
    if (tid < s) red[tid] += red[tid + s];
    __syncthreads();
  }
  float rstd = 1.0f / sqrtf(red[0] * (1.0f / DIM) + 1e-5f);
  out[(size_t)row * DIM + tid] = d0 * rstd * w[tid] + b[tid];
  out[(size_t)row * DIM + tid + 256] = d1 * rstd * w[tid + 256] + b[tid + 256];
}

// ---------------- prefill tiled GEMM ----------------
// MODE: 1 = gelu(+bias), 2 = +bias +res, 3 = qkv epilogue (+bias, write q + KV caches)
template <int MODE>
__global__ __launch_bounds__(256) void gemm_kernel(const float* __restrict__ A,
                                                   const float* __restrict__ W,
                                                   const float* __restrict__ bias,
                                                   const float* __restrict__ res,
                                                   float* __restrict__ C, int M, int N, int K,
                                                   float* __restrict__ kcT,
                                                   float* __restrict__ vc) {
  const int BM = 64, BN = 64, BK = 16;
  __shared__ float As[BK][BM + 4];
  __shared__ float Ws[BK][BN];
  int tid = threadIdx.x;
  int bm = blockIdx.y * BM, bn = blockIdx.x * BN;
  int tr = tid / 16, tc = tid % 16;
  float acc[4][4];
#pragma unroll
  for (int i = 0; i < 4; i++)
#pragma unroll
    for (int j = 0; j < 4; j++) acc[i][j] = 0.f;

  for (int k0 = 0; k0 < K; k0 += BK) {
    for (int i = tid; i < BM * BK; i += 256) {
      int m = i / BK, kk = i % BK;
      As[kk][m] = A[(size_t)(bm + m) * K + k0 + kk];
    }
    for (int i = tid; i < BK * BN; i += 256) {
      int kk = i / BN, n = i % BN;
      Ws[kk][n] = W[(size_t)(k0 + kk) * N + bn + n];
    }
    __syncthreads();
#pragma unroll
    for (int kk = 0; kk < BK; ++kk) {
      float a[4], w[4];
#pragma unroll
      for (int i = 0; i < 4; i++) a[i] = As[kk][tr * 4 + i];
#pragma unroll
      for (int j = 0; j < 4; j++) w[j] = Ws[kk][tc * 4 + j];
#pragma unroll
      for (int i = 0; i < 4; i++)
#pragma unroll
        for (int j = 0; j < 4; j++) acc[i][j] += a[i] * w[j];
    }
    __syncthreads();
  }
#pragma unroll
  for (int i = 0; i < 4; i++) {
    int m = bm + tr * 4 + i;
#pragma unroll
    for (int j = 0; j < 4; j++) {
      int n = bn + tc * 4 + j;
      float v = acc[i][j] + (bias ? bias[n] : 0.f);
      if (MODE == 1) v = gelu_f(v);
      if (MODE == 2) v += res[(size_t)m * N + n];
      if (MODE == 3) {
        int b = m >> 6, t = m & 63;
        if (n < DIM) {
          C[(size_t)m * N + n] = v;  // q (only q region consumed)
        } else if (n < 2 * DIM) {
          int dd = n - DIM;
          kcT[((size_t)(b * NHEAD + (dd >> 6)) * HEADD + (dd & 63)) * TMAX + t] = v;
        } else {
          int dd = n - 2 * DIM;
          vc[((size_t)(b * NHEAD + (dd >> 6)) * TMAX + t) * HEADD + (dd & 63)] = v;
        }
      } else {
        C[(size_t)m * N + n] = v;
      }
    }
  }
}

// ---------------- prefill attention (K^T cache layout) ----------------
__global__ void k_attn_prefill(const float* __restrict__ qkv, const float* __restrict__ kcT,
                               const float* __restrict__ vc, float* __restrict__ o) {
  int blk = blockIdx.x;
  int q = blk % PROMPT_LEN;
  int bh = blk / PROMPT_LEN;
  int h = bh % NHEAD, b = bh / NHEAD;
  int tid = threadIdx.x;  // 64
  __shared__ float qs[HEADD];
  __shared__ float ps[PROMPT_LEN];
  qs[tid] = qkv[(size_t)(b * PROMPT_LEN + q) * 3 * DIM + h * HEADD + tid];
  __syncthreads();
  const float* kbT = kcT + (size_t)(b * NHEAD + h) * HEADD * TMAX;  // [64][80]
  const float* vb = vc + (size_t)(b * NHEAD + h) * TMAX * HEADD;    // [80][64]
  float s = -1e30f;
  if (tid <= q) {
    float a = 0.f;
    for (int d = 0; d < HEADD; ++d) a += qs[d] * kbT[d * TMAX + tid];
    s = a * ATT_SCALE;
  }
  float mx = s;
  for (int off = 32; off > 0; off >>= 1) mx = fmaxf(mx, __shfl_xor(mx, off));
  float e = (tid <= q) ? expf(s - mx) : 0.f;
  float sum = e;
  for (int off = 32; off > 0; off >>= 1) sum += __shfl_xor(sum, off);
  ps[tid] = e / sum;
  __syncthreads();
  float acc = 0.f;
  for (int t = 0; t <= q; ++t) acc += ps[t] * vb[t * HEADD + tid];
  o[(size_t)(b * PROMPT_LEN + q) * DIM + h * HEADD + tid] = acc;
}

// ================= persistent decode kernel =================

struct SmGemm {
  float sm[DIM * BATCH];  // 8192 floats, max SROWS*BATCH over all stages
  float wsum[8][BATCH];
  float wss[8][BATCH];
  float smean[BATCH], srstd[BATCH];
};
struct SmAttn {
  float qs[8][HEADD];
  float ps[8][TMAX];
};
struct SmUpd {
  float vred[512];
  int ired[512];
  int sh_tok, sh_pos;
};
union SmAll {
  SmGemm g;
  SmAttn a;
  SmUpd u;
};

// Grid barrier, master-broadcast, fence-free (r6-proven). 256 blocks:
// arrivals are concurrent relaxed stores; block 0 detects with 256 threads
// (thread i polls flag i, one pass), then releases the single `go` word.
__device__ __forceinline__ void gsync(unsigned* __restrict__ flags, unsigned* __restrict__ go,
                                      unsigned gen) {
  __syncthreads();
  if (threadIdx.x == 0) sta_u(&flags[(unsigned)blockIdx.x * FSTRIDE], gen);
  if (blockIdx.x == 0) {
    if (threadIdx.x < GRIDN) {
      while (lda_u(&flags[threadIdx.x * FSTRIDE]) < gen) __builtin_amdgcn_s_sleep(1);
    }
    __syncthreads();  // all arrivals observed by block 0
    if (threadIdx.x == 0) sta_u(go, gen);
  }
  if (threadIdx.x == 0) {
    while (lda_u(go) < gen) __builtin_amdgcn_s_sleep(1);
  }
  __syncthreads();
}

// ---------------- decode skinny GEMM stage (device fn; 512 threads) ----------------
// C[16,N] = A^T[16,K] @ W[K,N]. A ([K][16]) is built in LDS from:
//   SRC_PLAIN: src            SRC_LN: ln(src + sum parts) (full-K stage; opt. write xd)
//   SRC_GELU: gelu(sum parts)
// 8 waves = 2 batch-groups x 4 k-chunks. KB = cross-block split-K (partials out,
// bias folded into partial kb==0). LAYOUT: 0 row-major [kb][16][N], 1 transposed [kb][N][16].
// Cross-block activations via relaxed agent atomics; weights plain cached loads.
template <int KB, int SRC, int P, int LAYOUT, bool BIAS, bool XDW, int N, int K>
__device__ __forceinline__ void skinny_stage(SmGemm& S, int bx, int by,
                                             const float* __restrict__ src,
                                             const float* __restrict__ parts,
                                             const float* __restrict__ lnw,
                                             const float* __restrict__ lnb,
                                             const float* __restrict__ bias,
                                             const float* __restrict__ W, float* __restrict__ out,
                                             float* __restrict__ xdout) {
  constexpr int KRANGE = K / KB;
  constexpr int SROWS = (SRC == SRC_LN) ? K : KRANGE;
  float* sm = S.sm;
  const int tid = threadIdx.x;
  const int base_row = (SRC == SRC_LN) ? 0 : by * KRANGE;

  // ---- stage ----
  {
    const float4* s4 = (const float4*)src;
    float4* d4 = (float4*)sm;
    constexpr int NF4 = SROWS * BATCH / 4;
    for (int i = tid; i < NF4; i += 512) {
      int gi = base_row * (BATCH / 4) + i;
      float4 v;
      if (SRC == SRC_GELU) {
        v = make_float4(0.f, 0.f, 0.f, 0.f);
      } else {
        v = lda4(s4 + gi);
      }
#pragma unroll
      for (int p = 0; p < P; ++p) {
        const float4* p4 = (const float4*)(parts + (size_t)p * K * BATCH);
        float4 t = lda4(p4 + gi);
        v.x += t.x;
        v.y += t.y;
        v.z += t.z;
        v.w += t.w;
      }
      if (SRC == SRC_GELU) {
        v.x = gelu_f(v.x);
        v.y = gelu_f(v.y);
        v.z = gelu_f(v.z);
        v.w = gelu_f(v.w);
      }
      if (XDW) {
        if (bx == 0 && by == 0) sta4(((float4*)xdout) + gi, v);
      }
      d4[i] = v;
    }
  }
  if (SRC == SRC_LN) {
    __syncthreads();
    float s = 0.f, ss = 0.f;
#pragma unroll
    for (int j = 0; j < 16; ++j) {
      float v = sm[tid + 512 * j];
      s += v;
      ss += v * v;
    }
    s += __shfl_xor(s, 16);
    ss += __shfl_xor(ss, 16);
    s += __shfl_xor(s, 32);
    ss += __shfl_xor(ss, 32);
    int lane0 = tid & 63, w0 = tid >> 6;
    if (lane0 < BATCH) {
      S.wsum[w0][lane0] = s;
      S.wss[w0][lane0] = ss;
    }
    __syncthreads();
    if (tid < BATCH) {
      float ts = 0.f, tss = 0.f;
#pragma unroll
      for (int ww = 0; ww < 8; ++ww) {
        ts += S.wsum[ww][tid];
        tss += S.wss[ww][tid];
      }
      float m = ts * (1.0f / K);
      float var = tss * (1.0f / K) - m * m;
      S.smean[tid] = m;
      S.srstd[tid] = 1.0f / sqrtf(var + 1e-5f);
    }
    __syncthreads();
    float mb = S.smean[tid & 15];
    float rb = S.srstd[tid & 15];
#pragma unroll
    for (int j = 0; j < 16; ++j) {
      int idx = tid + 512 * j;
      int k = idx >> 4;
      sm[idx] = (sm[idx] - mb) * rb * lnw[k] + lnb[k];
    }
  }
  __syncthreads();

  // ---- K-loop ----
  const int lane = tid & 63;
  const int w = tid >> 6;
  const int bw = w & 1;
  const int kw = w >> 1;
  constexpr int KCH = KRANGE / 4;
  const int col = bx * 64 + lane;
  const float* Wp = W + (size_t)(by * KRANGE + kw * KCH) * N + col;
  const int fbase = ((SRC == SRC_LN) ? by * KRANGE : 0) + kw * KCH;
  float acc[8];
#pragma unroll
  for (int i = 0; i < 8; ++i) acc[i] = 0.f;
  for (int k = 0; k < KCH; k += 8) {
    float wv[8];
#pragma unroll
    for (int u = 0; u < 8; ++u) wv[u] = Wp[(size_t)(k + u) * N];
#pragma unroll
    for (int u = 0; u < 8; ++u) {
      const float4* a4 = (const float4*)&sm[(fbase + k + u) * BATCH + bw * 8];
      float4 A0 = a4[0], A1 = a4[1];
      acc[0] = fmaf(A0.x, wv[u], acc[0]);
      acc[1] = fmaf(A0.y, wv[u], acc[1]);
      acc[2] = fmaf(A0.z, wv[u], acc[2]);
      acc[3] = fmaf(A0.w, wv[u], acc[3]);
      acc[4] = fmaf(A1.x, wv[u], acc[4]);
      acc[5] = fmaf(A1.y, wv[u], acc[5]);
      acc[6] = fmaf(A1.z, wv[u], acc[6]);
      acc[7] = fmaf(A1.w, wv[u], acc[7]);
    }
  }
  __syncthreads();
#pragma unroll
  for (int i = 0; i < 8; ++i) sm[(w * 8 + i) * 64 + lane] = acc[i];
  __syncthreads();
  for (int o = tid; o < BATCH * 64; o += 512) {
    int b, gn_l;
    if (LAYOUT == 1) {
      b = o & 15;
      gn_l = o >> 4;
    } else {
      b = o >> 6;
      gn_l = o & 63;
    }
    int bw2 = b >> 3, bi = b & 7;
    float v = 0.f;
#pragma unroll
    for (int k2 = 0; k2 < 4; ++k2) v += sm[(((k2 * 2 + bw2) * 8) + bi) * 64 + gn_l];
    int gn = bx * 64 + gn_l;
    if (BIAS && by == 0) v += bias[gn];
    if (KB == 1 && LAYOUT == 0)
      sta_f(&out[(size_t)b * N + gn], v);
    else if (LAYOUT == 0)
      sta_f(&out[((size_t)by * BATCH + b) * N + gn], v);
    else
      sta_f(&out[(size_t)by * N * BATCH + (size_t)gn * BATCH + b], v);
  }
  // a block may run another virtual tile right after this one: ensure all waves
  // finished reading sm before the next tile's staging overwrites it.
  __syncthreads();
}

// ---------------- decode attention stage (8 waves/block, wave = one (b,h)) ----------------
// Sums 4 qkv partials. KV cache slices for (b,h) touched by the SAME block
// every step (stable vb mapping) -> plain cached KV is safe.
__device__ __forceinline__ void attn_stage(SmAttn& S, int blk, const float* __restrict__ qp,
                                           const int* __restrict__ lens, float* __restrict__ kcT,
                                           float* __restrict__ vc, float* __restrict__ ot) {
  const int tid = threadIdx.x;
  const int d = tid & 63;
  const int wv = tid >> 6;
  const int bh = blk * 8 + wv;  // = b*NHEAD + h
  const int h = bh % NHEAD, b = bh / NHEAD;
  int p = lda_i(&lens[b]) - 1;
  if (p < 0) p = 0;
  if (p > TMAX - 1) p = TMAX - 1;
  float qv = 0.f, kself = 0.f, vself = 0.f;
#pragma unroll
  for (int j = 0; j < 4; ++j) {
    const float* qj = qp + (size_t)j * BATCH * 3 * DIM + (size_t)b * 3 * DIM + h * HEADD;
    qv += lda_f(qj + d);
    kself += lda_f(qj + DIM + d);
    vself += lda_f(qj + 2 * DIM + d);
  }
  float* kT = kcT + (size_t)bh * HEADD * TMAX;  // [64][80]
  float* vb = vc + (size_t)bh * TMAX * HEADD;   // [80][64]
  kT[d * TMAX + p] = kself;
  vb[p * HEADD + d] = vself;
  float* qs = S.qs[wv];
  float* ps = S.ps[wv];
  qs[d] = qv;
  __syncthreads();
  float pd = qv * kself;
  for (int off = 32; off > 0; off >>= 1) pd += __shfl_xor(pd, off);
  float selfdot = pd * ATT_SCALE;
  float s0 = -1e30f, s1 = -1e30f;
  int t1 = d + 64;
  if (d < p) {
    float a = 0.f;
    for (int dd = 0; dd < HEADD; ++dd) a += qs[dd] * kT[dd * TMAX + d];
    s0 = a * ATT_SCALE;
  } else if (d == p) {
    s0 = selfdot;
  }
  if (t1 < p) {
    float a = 0.f;
    for (int dd = 0; dd < HEADD; ++dd) a += qs[dd] * kT[dd * TMAX + t1];
    s1 = a * ATT_SCALE;
  } else if (t1 == p) {
    s1 = selfdot;
  }
  float mx = fmaxf(s0, s1);
  for (int off = 32; off > 0; off >>= 1) mx = fmaxf(mx, __shfl_xor(mx, off));
  float e0 = (d <= p) ? expf(s0 - mx) : 0.f;
  float e1 = (t1 <= p) ? expf(s1 - mx) : 0.f;
  float sum = e0 + e1;
  for (int off = 32; off > 0; off >>= 1) sum += __shfl_xor(sum, off);
  float inv = 1.f / sum;
  ps[d] = e0 * inv;
  if (d < TMAX - 64) ps[t1] = e1 * inv;
  __syncthreads();
  float acc = 0.f;
  for (int t = 0; t < p; ++t) acc += ps[t] * vb[t * HEADD + d];
  acc += ps[p] * vself;
  sta_f(&ot[(size_t)(h * HEADD + d) * BATCH + b], acc);
  __syncthreads();
}

// ---------------- decode update stage (512 threads, one batch element) ----------------
// Sums the 2 logits split-K partials inline.
__device__ __forceinline__ void update_stage(SmUpd& S, int b, const float* __restrict__ logits,
                                             int* ids, int* lens, int* fin, float* csum,
                                             float* ccnt, float* out_gen, int step,
                                             const float* __restrict__ wte,
                                             const float* __restrict__ wpe, float* xdT) {
  const int tid = threadIdx.x;
  const float* lr = logits + (size_t)b * VOCAB;
  const float* lr2 = lr + (size_t)BATCH * VOCAB;
  float best = -1e30f;
  int besti = 0;
  for (int i = tid; i < VOCAB; i += 512) {
    float v = lda_f(&lr[i]) + lda_f(&lr2[i]);
    if (v > best) {
      best = v;
      besti = i;
    }
  }
  S.vred[tid] = best;
  S.ired[tid] = besti;
  __syncthreads();
  for (int s = 256; s > 0; s >>= 1) {
    if (tid < s) {
      if (S.vred[tid + s] > S.vred[tid] ||
          (S.vred[tid + s] == S.vred[tid] && S.ired[tid + s] < S.ired[tid])) {
        S.vred[tid] = S.vred[tid + s];
        S.ired[tid] = S.ired[tid + s];
      }
    }
    __syncthreads();
  }
  float mx = S.vred[0];
  int top = S.ired[0];
  __syncthreads();
  float se = 0.f;
  for (int i = tid; i < VOCAB; i += 512)
    se += expf(lda_f(&lr[i]) + lda_f(&lr2[i]) - mx);
  S.vred[tid] = se;
  __syncthreads();
  for (int s = 256; s > 0; s >>= 1) {
    if (tid < s) S.vred[tid] += S.vred[tid + s];
    __syncthreads();
  }
  if (tid == 0) {
    float top_p = 1.f / S.vred[0];
    int l = lda_i(&lens[b]);
    int fb = lda_i(&fin[b]);
    bool active = (!fb) && (l < TMAX);
    if (active) {
      sta_f(&csum[b], lda_f(&csum[b]) + top_p);
      sta_f(&ccnt[b], lda_f(&ccnt[b]) + 1.f);
    }
    bool is_end = (top == 3) || (top == 0);
    bool wr = active && !is_end;
    if (wr) {
      sta_i(&ids[b * TMAX + l], top);
      sta_i(&lens[b], l + 1);
    }
    if (active && is_end) sta_i(&fin[b], 1);
    out_gen[b * NNEW + step] = wr ? (float)top : 0.f;
    int l2 = wr ? l + 1 : l;
    int pn = l2 - 1;
    if (pn < 0) pn = 0;
    if (pn > TMAX - 1) pn = TMAX - 1;
    S.sh_pos = pn;
    S.sh_tok = wr ? top : lda_i(&ids[b * TMAX + pn]);
  }
  __syncthreads();
  int tok = S.sh_tok, pn = S.sh_pos;
  sta_f(&xdT[(size_t)tid * BATCH + b],
        wte[(size_t)tok * DIM + tid] + wpe[(size_t)pn * DIM + tid]);
  __syncthreads();
}

struct DecArgs {
  const float *wte, *wpe, *ln1_w, *ln1_b, *qkv_w, *qkv_b, *ao_w, *ao_b, *ln2_w, *ln2_b;
  const float *fc_w, *fc_b, *pr_w, *pr_b, *lnf_w, *lnf_b, *lm_w;
  int *ids, *lens, *fin;
  float *csum, *ccnt;
  float *kc, *vc;
  float *xd0, *xd1, *ot, *qkp, *aop, *fcp, *prp, *logits;
  float* out;
  unsigned *flags, *go;
};

__global__ __launch_bounds__(512) void k_decode(DecArgs a) {
  __shared__ SmAll sm;
  const int blk = blockIdx.x;
  const int tid = threadIdx.x;
  const size_t kvstride = (size_t)BATCH * NHEAD * TMAX * HEADD;
  unsigned gen = 0;

  // embed0: xd0[d][b] = wte[tok] + wpe[pos]  (k_init data visible via kernel boundary)
  if (blk < BATCH) {
    int b = blk;
    int p = a.lens[b] - 1;
    if (p < 0) p = 0;
    if (p > TMAX - 1) p = TMAX - 1;
    int tok = a.ids[b * TMAX + p];
    sta_f(&a.xd0[(size_t)tid * BATCH + b],
          a.wte[(size_t)tok * DIM + tid] + a.wpe[(size_t)p * DIM + tid]);
  }
  gsync(a.flags, a.go, ++gen);

  for (int s = 0; s < NNEW; ++s) {
    for (int l = 0; l < NLAYER; ++l) {
      float* kc = a.kc + (size_t)l * kvstride;
      float* vc = a.vc + (size_t)l * kvstride;
      // QKV: ln1(xd) @ qkv_w -> 4 row-major partials [4][16][1536]  (96 tiles)
      for (int vb = blk; vb < 96; vb += GRIDN) {
        if (l == 0)
          skinny_stage<4, SRC_LN, 0, 0, true, false, 3 * DIM, DIM>(
              sm.g, vb % 24, vb / 24, a.xd0, nullptr, a.ln1_w + l * DIM, a.ln1_b + l * DIM,
              a.qkv_b + (size_t)l * 3 * DIM, a.qkv_w + (size_t)l * DIM * 3 * DIM, a.qkp, nullptr);
        else
          skinny_stage<4, SRC_LN, 8, 0, true, true, 3 * DIM, DIM>(
              sm.g, vb % 24, vb / 24, a.xd1, a.prp, a.ln1_w + l * DIM, a.ln1_b + l * DIM,
              a.qkv_b + (size_t)l * 3 * DIM, a.qkv_w + (size_t)l * DIM * 3 * DIM, a.qkp, a.xd0);
      }
      gsync(a.flags, a.go, ++gen);
      // attention: sums 4 qkv partials, appends KV, Ot[512][16]  (16 tiles)
      for (int vb = blk; vb < 16; vb += GRIDN)
        attn_stage(sm.a, vb, a.qkp, a.lens, kc, vc, a.ot);
      gsync(a.flags, a.go, ++gen);
      // AO: Ot @ ao_w -> 4 transposed partials [4][512][16]  (32 tiles)
      for (int vb = blk; vb < 32; vb += GRIDN)
        skinny_stage<4, SRC_PLAIN, 0, 1, true, false, DIM, DIM>(
            sm.g, vb % 8, vb / 8, a.ot, nullptr, nullptr, nullptr, a.ao_b + (size_t)l * DIM,
            a.ao_w + (size_t)l * DIM * DIM, a.aop, nullptr);
      gsync(a.flags, a.go, ++gen);
      // FC: ln2(xd0 + 4 ao partials) @ fc_w -> 4 transposed partials; write xd1  (128 tiles)
      for (int vb = blk; vb < 128; vb += GRIDN)
        skinny_stage<4, SRC_LN, 4, 1, true, true, 4 * DIM, DIM>(
            sm.g, vb % 32, vb / 32, a.xd0, a.aop, a.ln2_w + l * DIM, a.ln2_b + l * DIM,
            a.fc_b + (size_t)l * 4 * DIM, a.fc_w + (size_t)l * DIM * 4 * DIM, a.fcp, a.xd1);
      gsync(a.flags, a.go, ++gen);
      // PR: gelu(sum 4 fc partials) @ pr_w -> 8 transposed partials [8][512][16]  (64 tiles)
      for (int vb = blk; vb < 64; vb += GRIDN)
        skinny_stage<8, SRC_GELU, 4, 1, true, false, DIM, 4 * DIM>(
            sm.g, vb % 8, vb / 8, nullptr, a.fcp, nullptr, nullptr, a.pr_b + (size_t)l * DIM,
            a.pr_w + (size_t)l * 4 * DIM * DIM, a.prp, nullptr);
      gsync(a.flags, a.go, ++gen);
    }
    // logits = lnf(xd1 + 8 pr partials)^T @ lm_w -> 2 partials [2][16][8000]  (250 tiles)
    for (int vb = blk; vb < 2 * (VOCAB / 64); vb += GRIDN)
      skinny_stage<2, SRC_LN, 8, 0, false, false, VOCAB, DIM>(
          sm.g, vb % 125, vb / 125, a.xd1, a.prp, a.lnf_w, a.lnf_b, nullptr, a.lm_w, a.logits,
          nullptr);
    gsync(a.flags, a.go, ++gen);
    // update state + embed next token -> xd0  (16 tiles)
    for (int vb = blk; vb < BATCH; vb += GRIDN)
      update_stage(sm.u, vb, a.logits, a.ids, a.lens, a.fin, a.csum, a.ccnt, a.out, s, a.wte,
                   a.wpe, a.xd0);
    gsync(a.flags, a.go, ++gen);
  }
  // finalize confidences
  if (blk == 0 && tid < BATCH)
    a.out[BATCH * NNEW + tid] = lda_f(&a.csum[tid]) / fmaxf(lda_f(&a.ccnt[tid]), 1.f);
}

// ---------------- host launch ----------------
extern "C" void kernel_launch(void* const* d_in, const int* in_sizes, int n_in, void* d_out,
                              int out_size, void* d_ws, size_t ws_size, hipStream_t stream) {
  const float* wte = (const float*)d_in[0];
  const float* wpe = (const float*)d_in[1];
  const float* ln1_w = (const float*)d_in[2];
  const float* ln1_b = (const float*)d_in[3];
  const float* qkv_w = (const float*)d_in[4];
  const float* qkv_b = (const float*)d_in[5];
  const float* ao_w = (const float*)d_in[6];
  const float* ao_b = (const float*)d_in[7];
  const float* ln2_w = (const float*)d_in[8];
  const float* ln2_b = (const float*)d_in[9];
  const float* fc_w = (const float*)d_in[10];
  const float* fc_b = (const float*)d_in[11];
  const float* pr_w = (const float*)d_in[12];
  const float* pr_b = (const float*)d_in[13];
  const float* lnf_w = (const float*)d_in[14];
  const float* lnf_b = (const float*)d_in[15];
  const float* lm_w = (const float*)d_in[16];
  const int* ids_in = (const int*)d_in[17];
  const int* mask_in = (const int*)d_in[18];
  float* out = (float*)d_out;

  char* p = (char*)d_ws;
  auto carve = [&](size_t nbytes) {
    char* r = p;
    p += (nbytes + 255) & ~(size_t)255;
    return (void*)r;
  };
  int* w_ids = (int*)carve(BATCH * TMAX * 4);
  int* w_lens = (int*)carve(BATCH * 4);
  int* w_fin = (int*)carve(BATCH * 4);
  float* w_csum = (float*)carve(BATCH * 4);
  float* w_ccnt = (float*)carve(BATCH * 4);
  float* w_x = (float*)carve((size_t)BATCH * PROMPT_LEN * DIM * 4);
  float* w_h = (float*)carve((size_t)BATCH * PROMPT_LEN * DIM * 4);
  float* w_qkv = (float*)carve((size_t)BATCH * PROMPT_LEN * 3 * DIM * 4);
  float* w_att = (float*)carve((size_t)BATCH * PROMPT_LEN * DIM * 4);
  float* w_mlp = (float*)carve((size_t)BATCH * PROMPT_LEN * 4 * DIM * 4);
  float* w_kc = (float*)carve((size_t)NLAYER * BATCH * NHEAD * TMAX * HEADD * 4);
  float* w_vc = (float*)carve((size_t)NLAYER * BATCH * NHEAD * TMAX * HEADD * 4);
  float* w_xd0 = (float*)carve((size_t)DIM * BATCH * 4);
  float* w_xd1 = (float*)carve((size_t)DIM * BATCH * 4);
  float* w_ot = (float*)carve((size_t)DIM * BATCH * 4);
  float* w_qkp = (float*)carve((size_t)4 * BATCH * 3 * DIM * 4);
  float* w_aop = (float*)carve((size_t)4 * DIM * BATCH * 4);
  float* w_fcp = (float*)carve((size_t)4 * 4 * DIM * BATCH * 4);
  float* w_prp = (float*)carve((size_t)8 * DIM * BATCH * 4);
  float* w_logits = (float*)carve((size_t)2 * BATCH * VOCAB * 4);
  unsigned* w_flags = (unsigned*)carve((size_t)GRIDN * FSTRIDE * 4);
  unsigned* w_go = (unsigned*)carve(256);

  const int M = BATCH * PROMPT_LEN;  // 1024
  const size_t kvstride = (size_t)BATCH * NHEAD * TMAX * HEADD;

  k_init<<<1, 256, 0, stream>>>(ids_in, mask_in, w_ids, w_lens, w_fin, w_csum, w_ccnt, w_flags,
                                w_go);
  k_embed_prefill<<<M, 256, 0, stream>>>(w_ids, wte, wpe, w_x);

  for (int l = 0; l < NLAYER; ++l) {
    float* kc = w_kc + (size_t)l * kvstride;
    float* vc = w_vc + (size_t)l * kvstride;
    k_layernorm<<<M, 256, 0, stream>>>(w_x, ln1_w + l * DIM, ln1_b + l * DIM, w_h);
    gemm_kernel<3><<<dim3(3 * DIM / 64, M / 64), 256, 0, stream>>>(
        w_h, qkv_w + (size_t)l * DIM * 3 * DIM, qkv_b + (size_t)l * 3 * DIM, nullptr, w_qkv, M,
        3 * DIM, DIM, kc, vc);
    k_attn_prefill<<<BATCH * NHEAD * PROMPT_LEN, 64, 0, stream>>>(w_qkv, kc, vc, w_att);
    gemm_kernel<2><<<dim3(DIM / 64, M / 64), 256, 0, stream>>>(
        w_att, ao_w + (size_t)l * DIM * DIM, ao_b + (size_t)l * DIM, w_x, w_x, M, DIM, DIM,
        nullptr, nullptr);
    k_layernorm<<<M, 256, 0, stream>>>(w_x, ln2_w + l * DIM, ln2_b + l * DIM, w_h);
    gemm_kernel<1><<<dim3(4 * DIM / 64, M / 64), 256, 0, stream>>>(
        w_h, fc_w + (size_t)l * DIM * 4 * DIM, fc_b + (size_t)l * 4 * DIM, nullptr, w_mlp, M,
        4 * DIM, DIM, nullptr, nullptr);
    gemm_kernel<2><<<dim3(DIM / 64, M / 64), 256, 0, stream>>>(
        w_mlp, pr_w + (size_t)l * 4 * DIM * DIM, pr_b + (size_t)l * DIM, w_x, w_x, M, DIM,
        4 * DIM, nullptr, nullptr);
  }

  // ---- persistent decode: 256 blocks, fence-free scoped-atomic barriers ----
  DecArgs da;
  da.wte = wte;
  da.wpe = wpe;
  da.ln1_w = ln1_w;
  da.ln1_b = ln1_b;
  da.qkv_w = qkv_w;
  da.qkv_b = qkv_b;
  da.ao_w = ao_w;
  da.ao_b = ao_b;
  da.ln2_w = ln2_w;
  da.ln2_b = ln2_b;
  da.fc_w = fc_w;
  da.fc_b = fc_b;
  da.pr_w = pr_w;
  da.pr_b = pr_b;
  da.lnf_w = lnf_w;
  da.lnf_b = lnf_b;
  da.lm_w = lm_w;
  da.ids = w_ids;
  da.lens = w_lens;
  da.fin = w_fin;
  da.csum = w_csum;
  da.ccnt = w_ccnt;
  da.kc = w_kc;
  da.vc = w_vc;
  da.xd0 = w_xd0;
  da.xd1 = w_xd1;
  da.ot = w_ot;
  da.qkp = w_qkp;
  da.aop = w_aop;
  da.fcp = w_fcp;
  da.prp = w_prp;
  da.logits = w_logits;
  da.out = out;
  da.flags = w_flags;
  da.go = w_go;
  k_decode<<<GRIDN, 512, 0, stream>>>(da);
}